// Round 1
// baseline (313.434 us; speedup 1.0000x reference)
//
#include <hip/hip_runtime.h>

typedef unsigned short u16;
typedef unsigned int u32;
typedef __attribute__((ext_vector_type(8))) short bf16x8;
typedef __attribute__((ext_vector_type(8))) unsigned short u16x8;
typedef __attribute__((ext_vector_type(4))) float f32x4;

#define L_SEQ 2048
#define DMODEL 1024
#define NHEAD 16
#define EHEAD 64
#define FPROJ 7168
#define FCAT 5120
#define NEGINF -1e30f

__device__ __forceinline__ u16 f2bf(float f) {
  union { float f; u32 u; } v; v.f = f;
  u32 r = v.u + 0x7FFFu + ((v.u >> 16) & 1u);
  return (u16)(r >> 16);
}
__device__ __forceinline__ float bf2f(u16 h) {
  union { u32 u; float f; } v; v.u = ((u32)h) << 16;
  return v.f;
}
__device__ __forceinline__ void gld16(void* lds, const void* g) {
  __builtin_amdgcn_global_load_lds((const __attribute__((address_space(1))) u32*)g,
                                   (__attribute__((address_space(3))) u32*)lds, 16, 0, 0);
}

// ---------------- f32 -> bf16 convert (weights) ----------------
__global__ __launch_bounds__(256) void cvt_kernel(const float* __restrict__ in,
                                                  u16* __restrict__ out, int n4) {
  int i = blockIdx.x * 256 + threadIdx.x;
  if (i < n4) {
    float4 a = ((const float4*)in)[i];
    u16 o0 = f2bf(a.x), o1 = f2bf(a.y), o2 = f2bf(a.z), o3 = f2bf(a.w);
    u32 w0 = (u32)o0 | ((u32)o1 << 16);
    u32 w1 = (u32)o2 | ((u32)o3 << 16);
    ((u32*)out)[2 * i] = w0;
    ((u32*)out)[2 * i + 1] = w1;
  }
}

// ---------------- RMSNorm * (1+scale) -> bf16 ----------------
__global__ __launch_bounds__(256) void rmsnorm_kernel(const float* __restrict__ x,
                                                      const float* __restrict__ scale,
                                                      u16* __restrict__ xn) {
  int row = blockIdx.x;
  const float4 v = ((const float4*)(x + (size_t)row * DMODEL))[threadIdx.x];
  float ss = v.x * v.x + v.y * v.y + v.z * v.z + v.w * v.w;
#pragma unroll
  for (int m = 1; m < 64; m <<= 1) ss += __shfl_xor(ss, m);
  __shared__ float ws[4];
  if ((threadIdx.x & 63) == 0) ws[threadIdx.x >> 6] = ss;
  __syncthreads();
  float tot = ws[0] + ws[1] + ws[2] + ws[3];
  float r = rsqrtf(tot * (1.0f / DMODEL) + 1e-6f);
  float4 sc = ((const float4*)scale)[threadIdx.x];
  u16 o0 = f2bf(v.x * r * (1.0f + sc.x));
  u16 o1 = f2bf(v.y * r * (1.0f + sc.y));
  u16 o2 = f2bf(v.z * r * (1.0f + sc.z));
  u16 o3 = f2bf(v.w * r * (1.0f + sc.w));
  u32 w0 = (u32)o0 | ((u32)o1 << 16);
  u32 w1 = (u32)o2 | ((u32)o3 << 16);
  u32* dst = (u32*)(xn + (size_t)row * DMODEL);
  dst[2 * threadIdx.x] = w0;
  dst[2 * threadIdx.x + 1] = w1;
}

// ---------------- GEMM: C(M,N) = A(M,K) @ B(N,K)^T, bf16 inputs ----------------
// OUTMODE 0: write bf16 C.  OUTMODE 1: write f32 C = acc + skip.
template <int OUTMODE>
__global__ __launch_bounds__(256) void gemm_bt(const u16* __restrict__ A,
                                               const u16* __restrict__ B,
                                               void* __restrict__ Cout,
                                               const float* __restrict__ skip,
                                               int M, int N, int K) {
  __shared__ u16 sA[128 * 32];
  __shared__ u16 sB[128 * 32];
  const int tid = threadIdx.x;
  const int lane = tid & 63;
  const int wid = tid >> 6;
  const int wr = wid >> 1, wc = wid & 1;
  const int bm = blockIdx.y, bn = blockIdx.x;

  f32x4 acc[4][4] = {};

  const int srow = tid >> 2;          // 0..63
  const int scol = (tid & 3) << 3;    // 0,8,16,24 (elements)
  const u16* ga = A + (size_t)(bm * 128 + srow) * K + scol;
  const u16* gb = B + (size_t)(bn * 128 + srow) * K + scol;
  u16* la = sA + tid * 8;
  u16* lb = sB + tid * 8;

  const int frow = lane & 15;
  const int kf8 = (lane >> 4) * 8;

  for (int kt = 0; kt < K; kt += 32) {
    __syncthreads();
    gld16(la, ga + kt);
    gld16(la + 2048, ga + (size_t)64 * K + kt);
    gld16(lb, gb + kt);
    gld16(lb + 2048, gb + (size_t)64 * K + kt);
    __syncthreads();
    bf16x8 af[4], bfr[4];
#pragma unroll
    for (int m = 0; m < 4; ++m) {
      int row = wr * 64 + m * 16 + frow;
      af[m] = *(const bf16x8*)(sA + row * 32 + kf8);
    }
#pragma unroll
    for (int n = 0; n < 4; ++n) {
      int row = wc * 64 + n * 16 + frow;
      bfr[n] = *(const bf16x8*)(sB + row * 32 + kf8);
    }
#pragma unroll
    for (int m = 0; m < 4; ++m)
#pragma unroll
      for (int n = 0; n < 4; ++n)
        acc[m][n] = __builtin_amdgcn_mfma_f32_16x16x32_bf16(af[m], bfr[n], acc[m][n], 0, 0, 0);
  }

  const int r0 = (lane >> 4) * 4;
  const int c0 = lane & 15;
#pragma unroll
  for (int m = 0; m < 4; ++m) {
#pragma unroll
    for (int n = 0; n < 4; ++n) {
      int grow = bm * 128 + wr * 64 + m * 16 + r0;
      int gcol = bn * 128 + wc * 64 + n * 16 + c0;
      if (OUTMODE == 0) {
        u16* C = (u16*)Cout;
#pragma unroll
        for (int r = 0; r < 4; ++r)
          C[(size_t)(grow + r) * N + gcol] = f2bf(acc[m][n][r]);
      } else {
        float* C = (float*)Cout;
#pragma unroll
        for (int r = 0; r < 4; ++r) {
          size_t idx = (size_t)(grow + r) * N + gcol;
          C[idx] = acc[m][n][r] + skip[idx];
        }
      }
    }
  }
}

// ---------------- q/k norm + RoPE + v copy ----------------
__global__ __launch_bounds__(64) void qkv_prep(const u16* __restrict__ proj,
                                               const float* __restrict__ theta,
                                               const float* __restrict__ attn_scale,
                                               u16* __restrict__ qb, u16* __restrict__ kb,
                                               u16* __restrict__ vb) {
  const int l = blockIdx.x;
  const int hd = blockIdx.y;
  const int e = threadIdx.x;
  const u16* pr = proj + (size_t)l * FPROJ + hd * EHEAD + e;
  float q = bf2f(pr[0]);
  float k = bf2f(pr[DMODEL]);
  float v = bf2f(pr[2 * DMODEL]);
  float sq = q * q, sk = k * k;
#pragma unroll
  for (int m = 1; m < 64; m <<= 1) {
    sq += __shfl_xor(sq, m);
    sk += __shfl_xor(sk, m);
  }
  float s = sqrtf(attn_scale[hd]);
  q *= s * rsqrtf(sq + 1e-6f);
  k *= s * rsqrtf(sk + 1e-6f);
  float ang = theta[((size_t)hd * L_SEQ + l) * 32 + (e & 31)];
  float cs = __cosf(ang), sn = __sinf(ang);
  float qp = __shfl_xor(q, 32), kp = __shfl_xor(k, 32);
  float qr = (e < 32) ? (q * cs - qp * sn) : (q * cs + qp * sn);
  float kr = (e < 32) ? (k * cs - kp * sn) : (k * cs + kp * sn);
  size_t o = ((size_t)hd * L_SEQ + l) * EHEAD + e;
  qb[o] = f2bf(qr);
  kb[o] = f2bf(kr);
  vb[o] = f2bf(v);
}

// ---------------- GELU(up) -> h[:,1024:] ----------------
__global__ __launch_bounds__(256) void gelu_up_kernel(const u16* __restrict__ proj,
                                                      u16* __restrict__ h) {
  int i = blockIdx.x * 256 + threadIdx.x;  // over L*4096/8
  int l = i >> 9;
  int j8 = (i & 511) << 3;
  u16x8 a = *(const u16x8*)(proj + (size_t)l * FPROJ + 3 * DMODEL + j8);
  u16x8 o;
#pragma unroll
  for (int j = 0; j < 8; ++j) {
    float x = bf2f(a[j]);
    float y = 0.7978845608028654f * (x + 0.044715f * x * x * x);
    float t = __expf(-2.0f * fabsf(y));
    float th = (1.0f - t) / (1.0f + t);
    th = (y < 0.0f) ? -th : th;
    o[j] = f2bf(0.5f * x * (1.0f + th));
  }
  *(u16x8*)(h + (size_t)l * FCAT + DMODEL + j8) = o;
}

// ---------------- causal flash attention (bf16 MFMA) ----------------
__global__ __launch_bounds__(256) void attn_kernel(const u16* __restrict__ qb,
                                                   const u16* __restrict__ kb,
                                                   const u16* __restrict__ vb,
                                                   u16* __restrict__ hbuf) {
  const int qt = blockIdx.x;  // 0..31
  const int hd = blockIdx.y;  // 0..15
  const int tid = threadIdx.x, lane = tid & 63, w = tid >> 6;
  const int qbase = qt * 64;

  __shared__ u16 sK[32 * 64];      // XOR-swizzled rows (128B each)
  __shared__ u16 sVT[64 * 34];     // V^T, stride 34 (pad)
  __shared__ u16 sP[4][16 * 40];   // per-wave P tile, stride 40 (b128-aligned rows)

  const u16* Kh = kb + (size_t)hd * L_SEQ * EHEAD;
  const u16* Vh = vb + (size_t)hd * L_SEQ * EHEAD;
  const u16* Qh = qb + (size_t)hd * L_SEQ * EHEAD;

  const int frow = lane & 15;
  const int kf8 = (lane >> 4) * 8;
  const int qrow = qbase + w * 16 + frow;
  bf16x8 qf0 = *(const bf16x8*)(Qh + (size_t)qrow * EHEAD + kf8);
  bf16x8 qf1 = *(const bf16x8*)(Qh + (size_t)qrow * EHEAD + 32 + kf8);

  f32x4 acc[4] = {};
  float mrow[4], lrow[4];
#pragma unroll
  for (int r = 0; r < 4; ++r) { mrow[r] = NEGINF; lrow[r] = 0.0f; }

  const int nkt = qt * 2 + 2;
  const int srow = tid >> 3;        // 0..31
  const int se0 = (tid & 7) << 3;   // 0..56

  for (int kt = 0; kt < nkt; ++kt) {
    const int k0 = kt * 32;
    __syncthreads();
    // stage K (swizzled) and V^T
    u16x8 kv = *(const u16x8*)(Kh + (size_t)(k0 + srow) * EHEAD + se0);
    u16x8 vv = *(const u16x8*)(Vh + (size_t)(k0 + srow) * EHEAD + se0);
    {
      int byteoff = (srow * 128 + se0 * 2) ^ ((srow & 7) << 4);
      *(u16x8*)((char*)sK + byteoff) = kv;
#pragma unroll
      for (int j = 0; j < 8; ++j) sVT[(se0 + j) * 34 + srow] = vv[j];
    }
    __syncthreads();

    // S = Q @ K^T  (two 16-col fragments)
    f32x4 s[2];
#pragma unroll
    for (int c = 0; c < 2; ++c) {
      int krow = c * 16 + frow;
      int b0 = (krow * 128 + kf8 * 2) ^ ((krow & 7) << 4);
      int b1 = (krow * 128 + 64 + kf8 * 2) ^ ((krow & 7) << 4);
      bf16x8 kfr0 = *(const bf16x8*)((const char*)sK + b0);
      bf16x8 kfr1 = *(const bf16x8*)((const char*)sK + b1);
      f32x4 t = __builtin_amdgcn_mfma_f32_16x16x32_bf16(qf0, kfr0, (f32x4){0.f, 0.f, 0.f, 0.f}, 0, 0, 0);
      s[c] = __builtin_amdgcn_mfma_f32_16x16x32_bf16(qf1, kfr1, t, 0, 0, 0);
    }

    // mask + online softmax (row = (lane>>4)*4+r, col = frow)
    float p[2][4];
#pragma unroll
    for (int r = 0; r < 4; ++r) {
      int qg = qbase + w * 16 + (lane >> 4) * 4 + r;
#pragma unroll
      for (int c = 0; c < 2; ++c) {
        int kg = k0 + c * 16 + frow;
        if (kg > qg) s[c][r] = NEGINF;
      }
      float mx = fmaxf(s[0][r], s[1][r]);
#pragma unroll
      for (int msk = 1; msk < 16; msk <<= 1) mx = fmaxf(mx, __shfl_xor(mx, msk));
      float mnew = fmaxf(mrow[r], mx);
      float alpha = __expf(mrow[r] - mnew);
      float ps = 0.0f;
#pragma unroll
      for (int c = 0; c < 2; ++c) {
        p[c][r] = __expf(s[c][r] - mnew);
        ps += p[c][r];
      }
#pragma unroll
      for (int msk = 1; msk < 16; msk <<= 1) ps += __shfl_xor(ps, msk);
      lrow[r] = lrow[r] * alpha + ps;
      mrow[r] = mnew;
#pragma unroll
      for (int n = 0; n < 4; ++n) acc[n][r] *= alpha;
    }

    // P -> LDS (C layout) -> A-operand layout
    u16* sp = sP[w];
#pragma unroll
    for (int c = 0; c < 2; ++c)
#pragma unroll
      for (int r = 0; r < 4; ++r)
        sp[((lane >> 4) * 4 + r) * 40 + c * 16 + frow] = f2bf(p[c][r]);
    asm volatile("s_waitcnt lgkmcnt(0)" ::: "memory");
    bf16x8 pa = *(const bf16x8*)(sp + frow * 40 + kf8);

    // PV: acc[n] += P @ V  (V^T frags via 4x b32)
#pragma unroll
    for (int n = 0; n < 4; ++n) {
      int e = n * 16 + frow;
      const u16* vp = sVT + e * 34 + kf8;
      bf16x8 vf;
      ((u32*)&vf)[0] = *(const u32*)(vp);
      ((u32*)&vf)[1] = *(const u32*)(vp + 2);
      ((u32*)&vf)[2] = *(const u32*)(vp + 4);
      ((u32*)&vf)[3] = *(const u32*)(vp + 6);
      acc[n] = __builtin_amdgcn_mfma_f32_16x16x32_bf16(pa, vf, acc[n], 0, 0, 0);
    }
  }

  // epilogue: h[:, hd*64 + e] = acc / l
#pragma unroll
  for (int n = 0; n < 4; ++n) {
#pragma unroll
    for (int r = 0; r < 4; ++r) {
      int qg = qbase + w * 16 + (lane >> 4) * 4 + r;
      int col = hd * EHEAD + n * 16 + frow;
      hbuf[(size_t)qg * FCAT + col] = f2bf(acc[n][r] / lrow[r]);
    }
  }
}

extern "C" void kernel_launch(void* const* d_in, const int* in_sizes, int n_in,
                              void* d_out, int out_size, void* d_ws, size_t ws_size,
                              hipStream_t stream) {
  const float* x = (const float*)d_in[0];
  const float* theta = (const float*)d_in[1];
  const float* scale = (const float*)d_in[2];
  const float* w_in = (const float*)d_in[3];
  const float* w_out = (const float*)d_in[4];
  const float* attn_scale = (const float*)d_in[5];
  float* out = (float*)d_out;

  char* ws = (char*)d_ws;
  u16* xn = (u16*)ws;        ws += (size_t)L_SEQ * DMODEL * 2;
  u16* w_in_b = (u16*)ws;    ws += (size_t)FPROJ * DMODEL * 2;
  u16* w_out_b = (u16*)ws;   ws += (size_t)DMODEL * FCAT * 2;
  u16* proj = (u16*)ws;      ws += (size_t)L_SEQ * FPROJ * 2;
  u16* qb = (u16*)ws;        ws += (size_t)NHEAD * L_SEQ * EHEAD * 2;
  u16* kb = (u16*)ws;        ws += (size_t)NHEAD * L_SEQ * EHEAD * 2;
  u16* vb = (u16*)ws;        ws += (size_t)NHEAD * L_SEQ * EHEAD * 2;
  u16* hb = (u16*)ws;        ws += (size_t)L_SEQ * FCAT * 2;

  cvt_kernel<<<7168, 256, 0, stream>>>(w_in, w_in_b, FPROJ * DMODEL / 4);
  cvt_kernel<<<5120, 256, 0, stream>>>(w_out, w_out_b, DMODEL * FCAT / 4);
  rmsnorm_kernel<<<L_SEQ, 256, 0, stream>>>(x, scale, xn);
  gemm_bt<0><<<dim3(FPROJ / 128, L_SEQ / 128), 256, 0, stream>>>(xn, w_in_b, proj, nullptr,
                                                                 L_SEQ, FPROJ, DMODEL);
  qkv_prep<<<dim3(L_SEQ, NHEAD), 64, 0, stream>>>(proj, theta, attn_scale, qb, kb, vb);
  gelu_up_kernel<<<L_SEQ * 512 / 256, 256, 0, stream>>>(proj, hb);
  attn_kernel<<<dim3(L_SEQ / 64, NHEAD), 256, 0, stream>>>(qb, kb, vb, hb);
  gemm_bt<1><<<dim3(DMODEL / 128, L_SEQ / 128), 256, 0, stream>>>(hb, w_out_b, out, x,
                                                                  L_SEQ, DMODEL, FCAT);
}

// Round 3
// 223.539 us; speedup vs baseline: 1.4021x; 1.4021x over previous
//
#include <hip/hip_runtime.h>

typedef unsigned short u16;
typedef unsigned int u32;
typedef __attribute__((ext_vector_type(8))) short bf16x8;
typedef __attribute__((ext_vector_type(8))) unsigned short u16x8;
typedef __attribute__((ext_vector_type(4))) float f32x4;
typedef __attribute__((ext_vector_type(16))) float f32x16;

#define L_SEQ 2048
#define DMODEL 1024
#define NHEAD 16
#define EHEAD 64
#define FPROJ 7168
#define FCAT 5120
#define NEGINF -1e30f

__device__ __forceinline__ u16 f2bf(float f) {
  union { float f; u32 u; } v; v.f = f;
  u32 r = v.u + 0x7FFFu + ((v.u >> 16) & 1u);
  return (u16)(r >> 16);
}
__device__ __forceinline__ float bf2f(u16 h) {
  union { u32 u; float f; } v; v.u = ((u32)h) << 16;
  return v.f;
}
__device__ __forceinline__ void gld16(void* lds, const void* g) {
  __builtin_amdgcn_global_load_lds((const __attribute__((address_space(1))) u32*)g,
                                   (__attribute__((address_space(3))) u32*)lds, 16, 0, 0);
}

// ---------------- f32 -> bf16 convert (weights) ----------------
__global__ __launch_bounds__(256) void cvt_kernel(const float* __restrict__ in,
                                                  u16* __restrict__ out, int n4) {
  int i = blockIdx.x * 256 + threadIdx.x;
  if (i < n4) {
    float4 a = ((const float4*)in)[i];
    u16 o0 = f2bf(a.x), o1 = f2bf(a.y), o2 = f2bf(a.z), o3 = f2bf(a.w);
    ((u32*)out)[2 * i] = (u32)o0 | ((u32)o1 << 16);
    ((u32*)out)[2 * i + 1] = (u32)o2 | ((u32)o3 << 16);
  }
}

// ---------------- RMSNorm * (1+scale) -> bf16 ----------------
__global__ __launch_bounds__(256) void rmsnorm_kernel(const float* __restrict__ x,
                                                      const float* __restrict__ scale,
                                                      u16* __restrict__ xn) {
  int row = blockIdx.x;
  const float4 v = ((const float4*)(x + (size_t)row * DMODEL))[threadIdx.x];
  float ss = v.x * v.x + v.y * v.y + v.z * v.z + v.w * v.w;
#pragma unroll
  for (int m = 1; m < 64; m <<= 1) ss += __shfl_xor(ss, m);
  __shared__ float ws[4];
  if ((threadIdx.x & 63) == 0) ws[threadIdx.x >> 6] = ss;
  __syncthreads();
  float tot = ws[0] + ws[1] + ws[2] + ws[3];
  float r = rsqrtf(tot * (1.0f / DMODEL) + 1e-6f);
  float4 sc = ((const float4*)scale)[threadIdx.x];
  u32 w0 = (u32)f2bf(v.x * r * (1.0f + sc.x)) | ((u32)f2bf(v.y * r * (1.0f + sc.y)) << 16);
  u32 w1 = (u32)f2bf(v.z * r * (1.0f + sc.z)) | ((u32)f2bf(v.w * r * (1.0f + sc.w)) << 16);
  u32* dst = (u32*)(xn + (size_t)row * DMODEL);
  dst[2 * threadIdx.x] = w0;
  dst[2 * threadIdx.x + 1] = w1;
}

// ---------------- GEMM: C(M,N) = A(M,K) @ B(N,K)^T, bf16 inputs ----------------
// OUTMODE 0: bf16 C.  OUTMODE 1: f32 C = acc + skip.  OUTMODE 2: f32 partial (split-K over gridDim.z)
template <int OUTMODE>
__global__ __launch_bounds__(256) void gemm_bt(const u16* __restrict__ A,
                                               const u16* __restrict__ B,
                                               void* __restrict__ Cout,
                                               const float* __restrict__ skip,
                                               int M, int N, int K) {
  __shared__ u16 sA[128 * 32];
  __shared__ u16 sB[128 * 32];
  const int tid = threadIdx.x;
  const int lane = tid & 63;
  const int wid = tid >> 6;
  const int wr = wid >> 1, wc = wid & 1;
  const int bm = blockIdx.y, bn = blockIdx.x;
  const int kper = K / gridDim.z;
  const int kbeg = blockIdx.z * kper;

  f32x4 acc[4][4] = {};

  const int srow = tid >> 2;
  const int scol = (tid & 3) << 3;
  const u16* ga = A + (size_t)(bm * 128 + srow) * K + scol;
  const u16* gb = B + (size_t)(bn * 128 + srow) * K + scol;
  u16* la = sA + tid * 8;
  u16* lb = sB + tid * 8;

  const int frow = lane & 15;
  const int kf8 = (lane >> 4) * 8;

  for (int kt = kbeg; kt < kbeg + kper; kt += 32) {
    __syncthreads();
    gld16(la, ga + kt);
    gld16(la + 2048, ga + (size_t)64 * K + kt);
    gld16(lb, gb + kt);
    gld16(lb + 2048, gb + (size_t)64 * K + kt);
    __syncthreads();
    bf16x8 af[4], bfr[4];
#pragma unroll
    for (int m = 0; m < 4; ++m)
      af[m] = *(const bf16x8*)(sA + (wr * 64 + m * 16 + frow) * 32 + kf8);
#pragma unroll
    for (int n = 0; n < 4; ++n)
      bfr[n] = *(const bf16x8*)(sB + (wc * 64 + n * 16 + frow) * 32 + kf8);
#pragma unroll
    for (int m = 0; m < 4; ++m)
#pragma unroll
      for (int n = 0; n < 4; ++n)
        acc[m][n] = __builtin_amdgcn_mfma_f32_16x16x32_bf16(af[m], bfr[n], acc[m][n], 0, 0, 0);
  }

  const int r0 = (lane >> 4) * 4;
  const int c0 = lane & 15;
#pragma unroll
  for (int m = 0; m < 4; ++m) {
#pragma unroll
    for (int n = 0; n < 4; ++n) {
      int grow = bm * 128 + wr * 64 + m * 16 + r0;
      int gcol = bn * 128 + wc * 64 + n * 16 + c0;
      if (OUTMODE == 0) {
        u16* C = (u16*)Cout;
#pragma unroll
        for (int r = 0; r < 4; ++r)
          C[(size_t)(grow + r) * N + gcol] = f2bf(acc[m][n][r]);
      } else if (OUTMODE == 1) {
        float* C = (float*)Cout;
#pragma unroll
        for (int r = 0; r < 4; ++r) {
          size_t idx = (size_t)(grow + r) * N + gcol;
          C[idx] = acc[m][n][r] + skip[idx];
        }
      } else {
        float* C = (float*)Cout + (size_t)blockIdx.z * M * N;
#pragma unroll
        for (int r = 0; r < 4; ++r)
          C[(size_t)(grow + r) * N + gcol] = acc[m][n][r];
      }
    }
  }
}

// ---------------- combine split-K partials + skip ----------------
__global__ __launch_bounds__(256) void combine_kernel(const float* __restrict__ p0,
                                                      const float* __restrict__ p1,
                                                      const float* __restrict__ x,
                                                      float* __restrict__ out, int n4) {
  int i = blockIdx.x * 256 + threadIdx.x;
  if (i < n4) {
    float4 a = ((const float4*)p0)[i];
    float4 b = ((const float4*)p1)[i];
    float4 c = ((const float4*)x)[i];
    float4 o = {a.x + b.x + c.x, a.y + b.y + c.y, a.z + b.z + c.z, a.w + b.w + c.w};
    ((float4*)out)[i] = o;
  }
}

// ---------------- q/k norm + RoPE + v copy ----------------
__global__ __launch_bounds__(256) void qkv_prep(const u16* __restrict__ proj,
                                                const float* __restrict__ theta,
                                                const float* __restrict__ attn_scale,
                                                u16* __restrict__ qb, u16* __restrict__ kb,
                                                u16* __restrict__ vb) {
  const int l = blockIdx.x * 4 + (threadIdx.x >> 6);
  const int hd = blockIdx.y;
  const int e = threadIdx.x & 63;
  const u16* pr = proj + (size_t)l * FPROJ + hd * EHEAD + e;
  float q = bf2f(pr[0]);
  float k = bf2f(pr[DMODEL]);
  float v = bf2f(pr[2 * DMODEL]);
  float sq = q * q, sk = k * k;
#pragma unroll
  for (int m = 1; m < 64; m <<= 1) {
    sq += __shfl_xor(sq, m);
    sk += __shfl_xor(sk, m);
  }
  float s = sqrtf(attn_scale[hd]);
  q *= s * rsqrtf(sq + 1e-6f);
  k *= s * rsqrtf(sk + 1e-6f);
  float ang = theta[((size_t)hd * L_SEQ + l) * 32 + (e & 31)];
  float cs = __cosf(ang), sn = __sinf(ang);
  float qp = __shfl_xor(q, 32), kp = __shfl_xor(k, 32);
  float qr = (e < 32) ? (q * cs - qp * sn) : (q * cs + qp * sn);
  float kr = (e < 32) ? (k * cs - kp * sn) : (k * cs + kp * sn);
  size_t o = ((size_t)hd * L_SEQ + l) * EHEAD + e;
  qb[o] = f2bf(qr);
  kb[o] = f2bf(kr);
  vb[o] = f2bf(v);
}

// ---------------- GELU(up) -> h[:,1024:] ----------------
__global__ __launch_bounds__(256) void gelu_up_kernel(const u16* __restrict__ proj,
                                                      u16* __restrict__ h) {
  int i = blockIdx.x * 256 + threadIdx.x;
  int l = i >> 9;
  int j8 = (i & 511) << 3;
  u16x8 a = *(const u16x8*)(proj + (size_t)l * FPROJ + 3 * DMODEL + j8);
  u16x8 o;
#pragma unroll
  for (int j = 0; j < 8; ++j) {
    float x = bf2f(a[j]);
    float y = 0.7978845608028654f * (x + 0.044715f * x * x * x);
    float t = __expf(-2.0f * fabsf(y));
    float th = (1.0f - t) / (1.0f + t);
    th = (y < 0.0f) ? -th : th;
    o[j] = f2bf(0.5f * x * (1.0f + th));
  }
  *(u16x8*)(h + (size_t)l * FCAT + DMODEL + j8) = o;
}

// ---------------- causal flash attention, 32x32 MFMA, swapped-QK^T ----------------
// 512 blocks x 128 threads. Block b: strip = 31 - (b>>4) (heavy-first), head = b&15.
// Wave w owns q rows [strip*64 + 32w, +32). 64-key tiles; K via global_load_lds with
// pre-swizzled source + XOR-swizzled reads; V^T reg-transposed with same swizzle.
// Softmax fully in-register (lane owns P-row for q = lane&31); PV as O^T = V^T @ P^T.
__global__ __launch_bounds__(128) void attn_kernel(const u16* __restrict__ qb,
                                                   const u16* __restrict__ kb,
                                                   const u16* __restrict__ vb,
                                                   u16* __restrict__ hbuf) {
  const int bid = blockIdx.x;
  const int strip = 31 - (bid >> 4);
  const int hd = bid & 15;
  const int tid = threadIdx.x;
  const int lane = tid & 63;
  const int w = tid >> 6;
  const int h = lane >> 5;
  const int ql = lane & 31;
  const int qg = strip * 64 + w * 32 + ql;

  __shared__ u16 sK[64 * 64];
  __shared__ u16 sVT[64 * 64];

  const u16* Kh = kb + (size_t)hd * L_SEQ * EHEAD;
  const u16* Vh = vb + (size_t)hd * L_SEQ * EHEAD;
  const u16* Qh = qb + (size_t)hd * L_SEQ * EHEAD;

  bf16x8 qf[4];
#pragma unroll
  for (int es = 0; es < 4; ++es)
    qf[es] = *(const bf16x8*)(Qh + (size_t)qg * EHEAD + es * 16 + h * 8);

  f32x16 oa[2] = {};
  float m = NEGINF, lsum = 0.0f;

  const int vk = (tid & 15) * 4;
  const int ve = (tid >> 4) * 8;
  const int ntile = strip + 1;

  for (int kt = 0; kt < ntile; ++kt) {
    const int k0 = kt * 64;
    __syncthreads();
    // stage K: linear LDS dest, inverse-swizzled global source (rule 21)
#pragma unroll
    for (int i = 0; i < 4; ++i) {
      int r = w * 32 + i * 8 + (lane >> 3);
      const u16* src = Kh + (size_t)(k0 + r) * EHEAD + (((lane & 7) ^ (r & 7)) << 3);
      gld16(sK + (w * 32 + i * 8) * 64 + lane * 8, src);
    }
    // stage V^T: reg transpose, packed b64 writes, XOR-swizzled rows
    u16x8 vr[4];
#pragma unroll
    for (int j = 0; j < 4; ++j)
      vr[j] = *(const u16x8*)(Vh + (size_t)(k0 + vk + j) * EHEAD + ve);
#pragma unroll
    for (int e = 0; e < 8; ++e) {
      int row = ve + e;
      int boff = row * 128 + ((((vk >> 3) ^ (row & 7)) << 4) | ((vk & 4) << 1));
      ushort4 pv;
      pv.x = vr[0][e]; pv.y = vr[1][e]; pv.z = vr[2][e]; pv.w = vr[3][e];
      *(ushort4*)((char*)sVT + boff) = pv;
    }
    __syncthreads();

    // S^T = K @ Q^T : lane holds P[k-set][q = ql]
    f32x16 st[2];
#pragma unroll
    for (int t = 0; t < 2; ++t) {
      f32x16 a = {};
#pragma unroll
      for (int es = 0; es < 4; ++es) {
        int row = t * 32 + ql;
        int boff = row * 128 + (((es * 2 + h) ^ (row & 7)) << 4);
        bf16x8 kf = *(const bf16x8*)((const char*)sK + boff);
        a = __builtin_amdgcn_mfma_f32_32x32x16_bf16(kf, qf[es], a, 0, 0, 0);
      }
      st[t] = a;
    }

    // online softmax, fully in-register (row split lane <-> lane^32)
    float p[2][16];
    float mx = NEGINF;
    const bool edge = (kt == strip);
#pragma unroll
    for (int t = 0; t < 2; ++t)
#pragma unroll
      for (int r = 0; r < 16; ++r) {
        float v = st[t][r];
        if (edge) {
          int kg = k0 + t * 32 + (r & 3) + ((r >> 2) << 3) + h * 4;
          v = (kg > qg) ? NEGINF : v;
        }
        p[t][r] = v;
        mx = fmaxf(mx, v);
      }
    mx = fmaxf(mx, __shfl_xor(mx, 32));
    float mnew = fmaxf(m, mx);
    float alpha = __expf(m - mnew);
    float ps = 0.0f;
#pragma unroll
    for (int t = 0; t < 2; ++t)
#pragma unroll
      for (int r = 0; r < 16; ++r) {
        float e_ = __expf(p[t][r] - mnew);
        p[t][r] = e_;
        ps += e_;
      }
    ps += __shfl_xor(ps, 32);
    lsum = lsum * alpha + ps;
    m = mnew;
#pragma unroll
    for (int et = 0; et < 2; ++et)
#pragma unroll
      for (int r = 0; r < 16; ++r) oa[et][r] *= alpha;

    // pack P to bf16 pairs: pk_[t][i] = (p[2i], p[2i+1]); pair i holds within-t keys
    // {0,2,8,10,16,18,24,26}[i]..+1, each +4h.
    u32 pk_[2][8];
#pragma unroll
    for (int t = 0; t < 2; ++t)
#pragma unroll
      for (int i = 0; i < 8; ++i)
        pk_[t][i] = (u32)f2bf(p[t][2 * i]) | ((u32)f2bf(p[t][2 * i + 1]) << 16);

    // PV: oa[et] += V^T(32e x 16k) @ P^T(16k x 32q).
    // B frag word w holds keys ks*16 + 8h + {2w,2w+1}.
    // h=0 keeps pk[b+0],pk[b+1] (keys 0-3), needs partner's pk[b+0],pk[b+1] (keys 4-7);
    // h=1 keeps pk[b+2],pk[b+3] (keys 12-15), needs partner's pk[b+2],pk[b+3] (keys 8-11).
    // Each lane SENDS the complementary words its partner needs.
#pragma unroll
    for (int ks = 0; ks < 4; ++ks) {
      const int tp = ks >> 1, base = (ks & 1) * 4;
      u32 s0 = h ? pk_[tp][base + 0] : pk_[tp][base + 2];
      u32 s1 = h ? pk_[tp][base + 1] : pk_[tp][base + 3];
      u32 r0 = (u32)__shfl_xor((int)s0, 32);
      u32 r1 = (u32)__shfl_xor((int)s1, 32);
      union { u32 u[4]; bf16x8 v; } pf;
      pf.u[0] = h ? r0 : pk_[tp][base + 0];
      pf.u[1] = h ? r1 : pk_[tp][base + 1];
      pf.u[2] = h ? pk_[tp][base + 2] : r0;
      pf.u[3] = h ? pk_[tp][base + 3] : r1;
#pragma unroll
      for (int et = 0; et < 2; ++et) {
        int row = et * 32 + ql;
        int boff = row * 128 + (((ks * 2 + h) ^ (row & 7)) << 4);
        bf16x8 vf = *(const bf16x8*)((const char*)sVT + boff);
        oa[et] = __builtin_amdgcn_mfma_f32_32x32x16_bf16(vf, pf.v, oa[et], 0, 0, 0);
      }
    }
  }

  // epilogue: O[q][e] = oa[et][r]/lsum, e = (r&3)+8*(r>>2)+4h+32et -> 4-wide stores
  float rdiv = 1.0f / lsum;
  u16* orow = hbuf + (size_t)qg * FCAT + hd * EHEAD;
#pragma unroll
  for (int et = 0; et < 2; ++et)
#pragma unroll
    for (int g = 0; g < 4; ++g) {
      ushort4 ov;
      ov.x = f2bf(oa[et][4 * g + 0] * rdiv);
      ov.y = f2bf(oa[et][4 * g + 1] * rdiv);
      ov.z = f2bf(oa[et][4 * g + 2] * rdiv);
      ov.w = f2bf(oa[et][4 * g + 3] * rdiv);
      *(ushort4*)(orow + et * 32 + g * 8 + h * 4) = ov;
    }
}

extern "C" void kernel_launch(void* const* d_in, const int* in_sizes, int n_in,
                              void* d_out, int out_size, void* d_ws, size_t ws_size,
                              hipStream_t stream) {
  const float* x = (const float*)d_in[0];
  const float* theta = (const float*)d_in[1];
  const float* scale = (const float*)d_in[2];
  const float* w_in = (const float*)d_in[3];
  const float* w_out = (const float*)d_in[4];
  const float* attn_scale = (const float*)d_in[5];
  float* out = (float*)d_out;

  char* ws = (char*)d_ws;
  u16* xn = (u16*)ws;        ws += (size_t)L_SEQ * DMODEL * 2;
  u16* w_in_b = (u16*)ws;    ws += (size_t)FPROJ * DMODEL * 2;
  u16* w_out_b = (u16*)ws;   ws += (size_t)DMODEL * FCAT * 2;
  u16* proj = (u16*)ws;      ws += (size_t)L_SEQ * FPROJ * 2;
  u16* qb = (u16*)ws;        ws += (size_t)NHEAD * L_SEQ * EHEAD * 2;
  u16* kb = (u16*)ws;        ws += (size_t)NHEAD * L_SEQ * EHEAD * 2;
  u16* vb = (u16*)ws;        ws += (size_t)NHEAD * L_SEQ * EHEAD * 2;
  u16* hb = (u16*)ws;        ws += (size_t)L_SEQ * FCAT * 2;
  float* part = (float*)proj;  // reuse: proj's last reader (gelu/qkv_prep) precedes gemm2

  cvt_kernel<<<7168, 256, 0, stream>>>(w_in, w_in_b, FPROJ * DMODEL / 4);
  cvt_kernel<<<5120, 256, 0, stream>>>(w_out, w_out_b, DMODEL * FCAT / 4);
  rmsnorm_kernel<<<L_SEQ, 256, 0, stream>>>(x, scale, xn);
  gemm_bt<0><<<dim3(FPROJ / 128, L_SEQ / 128, 1), 256, 0, stream>>>(xn, w_in_b, proj, nullptr,
                                                                    L_SEQ, FPROJ, DMODEL);
  qkv_prep<<<dim3(L_SEQ / 4, NHEAD), 256, 0, stream>>>(proj, theta, attn_scale, qb, kb, vb);
  gelu_up_kernel<<<L_SEQ * 512 / 256, 256, 0, stream>>>(proj, hb);
  attn_kernel<<<512, 128, 0, stream>>>(qb, kb, vb, hb);
  gemm_bt<2><<<dim3(DMODEL / 128, L_SEQ / 128, 2), 256, 0, stream>>>(hb, w_out_b, part, nullptr,
                                                                     L_SEQ, DMODEL, FCAT);
  combine_kernel<<<L_SEQ * DMODEL / 4 / 256, 256, 0, stream>>>(part, part + (size_t)L_SEQ * DMODEL,
                                                               x, out, L_SEQ * DMODEL / 4);
}

// Round 4
// 206.722 us; speedup vs baseline: 1.5162x; 1.0813x over previous
//
#include <hip/hip_runtime.h>

typedef unsigned short u16;
typedef unsigned int u32;
typedef __attribute__((ext_vector_type(8))) short bf16x8;
typedef __attribute__((ext_vector_type(8))) unsigned short u16x8;
typedef __attribute__((ext_vector_type(4))) float f32x4;
typedef __attribute__((ext_vector_type(16))) float f32x16;

#define L_SEQ 2048
#define DMODEL 1024
#define NHEAD 16
#define EHEAD 64
#define FPROJ 7168
#define FCAT 5120
#define NEGINF -1e30f

__device__ __forceinline__ u16 f2bf(float f) {
  union { float f; u32 u; } v; v.f = f;
  u32 r = v.u + 0x7FFFu + ((v.u >> 16) & 1u);
  return (u16)(r >> 16);
}
__device__ __forceinline__ float bf2f(u16 h) {
  union { u32 u; float f; } v; v.u = ((u32)h) << 16;
  return v.f;
}
__device__ __forceinline__ void gld16(void* lds, const void* g) {
  __builtin_amdgcn_global_load_lds((const __attribute__((address_space(1))) u32*)g,
                                   (__attribute__((address_space(3))) u32*)lds, 16, 0, 0);
}

// ---------------- f32 -> bf16 convert (weights) ----------------
__global__ __launch_bounds__(256) void cvt_kernel(const float* __restrict__ in,
                                                  u16* __restrict__ out, int n4) {
  int i = blockIdx.x * 256 + threadIdx.x;
  if (i < n4) {
    float4 a = ((const float4*)in)[i];
    u16 o0 = f2bf(a.x), o1 = f2bf(a.y), o2 = f2bf(a.z), o3 = f2bf(a.w);
    ((u32*)out)[2 * i] = (u32)o0 | ((u32)o1 << 16);
    ((u32*)out)[2 * i + 1] = (u32)o2 | ((u32)o3 << 16);
  }
}

// ---------------- RMSNorm * (1+scale) -> bf16 ----------------
__global__ __launch_bounds__(256) void rmsnorm_kernel(const float* __restrict__ x,
                                                      const float* __restrict__ scale,
                                                      u16* __restrict__ xn) {
  int row = blockIdx.x;
  const float4 v = ((const float4*)(x + (size_t)row * DMODEL))[threadIdx.x];
  float ss = v.x * v.x + v.y * v.y + v.z * v.z + v.w * v.w;
#pragma unroll
  for (int m = 1; m < 64; m <<= 1) ss += __shfl_xor(ss, m);
  __shared__ float ws[4];
  if ((threadIdx.x & 63) == 0) ws[threadIdx.x >> 6] = ss;
  __syncthreads();
  float tot = ws[0] + ws[1] + ws[2] + ws[3];
  float r = rsqrtf(tot * (1.0f / DMODEL) + 1e-6f);
  float4 sc = ((const float4*)scale)[threadIdx.x];
  u32 w0 = (u32)f2bf(v.x * r * (1.0f + sc.x)) | ((u32)f2bf(v.y * r * (1.0f + sc.y)) << 16);
  u32 w1 = (u32)f2bf(v.z * r * (1.0f + sc.z)) | ((u32)f2bf(v.w * r * (1.0f + sc.w)) << 16);
  u32* dst = (u32*)(xn + (size_t)row * DMODEL);
  dst[2 * threadIdx.x] = w0;
  dst[2 * threadIdx.x + 1] = w1;
}

// ---------------- 256x256 8-phase GEMM: C(M,N) = A(M,K) @ B(N,K)^T, bf16 out ----------------
// 512 threads = 8 waves (1M x 8N). Wave wn: rows all 256, cols [wn*32,+32). BK=64.
// LDS 128KB: 2 dbuf x (A 256x64 + B 256x64) bf16, XOR-swizzled (row&7)<<4 via
// pre-swizzled global source (linear gld dest). 8 phases/iter = 2 K-tiles.
// Phase (hm,kh) reads A-half hm only -> A halves freed at 2-phase granularity.
// Counted vmcnt(2) at phases 4,8 only; raw s_barrier (no vmcnt drain); setprio on MFMA.
__device__ __forceinline__ void stage_half(u16* lds, const u16* g, int K, int tid) {
#pragma unroll
  for (int i = 0; i < 2; ++i) {
    int idx = tid + i * 512;                    // 0..1023 chunk of 16B
    int r = idx >> 3;                           // row 0..127
    int gcb = ((idx & 7) << 4) ^ ((r & 7) << 4);  // inverse-swizzled col byte
    gld16((char*)lds + idx * 16, (const char*)g + (size_t)r * K * 2 + gcb);
  }
}

#define GFENCE asm volatile("" ::: "memory")
#define VMW2 asm volatile("s_waitcnt vmcnt(2)" ::: "memory")
#define ST_A(BUF, T, HALF) stage_half(sA + (BUF) * 16384 + (HALF) * 8192, \
    Ab + (size_t)((HALF) * 128) * K + (T) * 64, K, tid)
#define ST_B(BUF, T, HALF) stage_half(sB + (BUF) * 16384 + (HALF) * 8192, \
    Bb + (size_t)((HALF) * 128) * K + (T) * 64, K, tid)

#define PHASE(HM, KH, BUFB, DOVM, STCODE) do { \
    const char* ab_ = (const char*)sA + (BUFB) * 32768 + (HM) * 16384 + frow * 128 + ((KH) ? co1 : co0); \
    const char* bb_ = (const char*)sB + (BUFB) * 32768 + (wn * 32 + frow) * 128 + ((KH) ? co1 : co0); \
    bf16x8 af_[8], bv_[2]; \
    _Pragma("unroll") \
    for (int mr = 0; mr < 8; ++mr) af_[mr] = *(const bf16x8*)(ab_ + mr * 2048); \
    bv_[0] = *(const bf16x8*)(bb_); \
    bv_[1] = *(const bf16x8*)(bb_ + 2048); \
    GFENCE; \
    STCODE; \
    if (DOVM) VMW2; \
    __builtin_amdgcn_s_barrier(); \
    __builtin_amdgcn_s_setprio(1); \
    _Pragma("unroll") \
    for (int mr = 0; mr < 8; ++mr) { \
      acc[(HM) * 8 + mr][0] = __builtin_amdgcn_mfma_f32_16x16x32_bf16(af_[mr], bv_[0], acc[(HM) * 8 + mr][0], 0, 0, 0); \
      acc[(HM) * 8 + mr][1] = __builtin_amdgcn_mfma_f32_16x16x32_bf16(af_[mr], bv_[1], acc[(HM) * 8 + mr][1], 0, 0, 0); \
    } \
    __builtin_amdgcn_s_setprio(0); \
    __builtin_amdgcn_s_barrier(); \
  } while (0)

__global__ __launch_bounds__(512, 2) void gemm256(const u16* __restrict__ A,
                                                  const u16* __restrict__ B,
                                                  u16* __restrict__ C,
                                                  int M, int N, int K) {
  __shared__ __align__(16) u16 sA[2 * 16384];
  __shared__ __align__(16) u16 sB[2 * 16384];
  const int tid = threadIdx.x;
  const int lane = tid & 63;
  const int wn = tid >> 6;
  const int frow = lane & 15;
  const int kbyte = ((lane >> 4) & 3) << 4;
  const int sw = (frow & 7) << 4;
  const int co0 = kbyte ^ sw;
  const int co1 = (64 | kbyte) ^ sw;

  const int nbx = N >> 8;
  const int v = (blockIdx.x & 7) * ((int)gridDim.x >> 3) + ((int)blockIdx.x >> 3);
  const int bm = v / nbx, bn = v % nbx;
  const u16* Ab = A + (size_t)(bm * 256) * K;
  const u16* Bb = B + (size_t)(bn * 256) * K;

  f32x4 acc[16][2] = {};

  const int NT = K >> 6;
  // prologue: tile0 {A0, B.h0, B.h1, A1}, tile1 {A0}
  ST_A(0, 0, 0); ST_B(0, 0, 0); ST_B(0, 0, 1); ST_A(0, 0, 1); ST_A(1, 1, 0);
  VMW2;
  __builtin_amdgcn_s_barrier();

  for (int kt = 0; kt < NT; kt += 2) {
    const int t1 = kt + 1;
    const int t2 = (kt + 2 >= NT) ? kt + 2 - NT : kt + 2;
    const int t3 = (kt + 3 >= NT) ? kt + 3 - NT : kt + 3;
    PHASE(0, 0, 0, 0, ST_B(1, t1, 0));
    PHASE(0, 1, 0, 0, ST_B(1, t1, 1));
    PHASE(1, 0, 0, 0, ST_A(1, t1, 1));
    PHASE(1, 1, 0, 1, ST_A(0, t2, 0));
    PHASE(0, 0, 1, 0, ST_B(0, t2, 0));
    PHASE(0, 1, 1, 0, ST_B(0, t2, 1));
    PHASE(1, 0, 1, 0, ST_A(0, t2, 1));
    PHASE(1, 1, 1, 1, ST_A(1, t3, 0));
  }

#pragma unroll
  for (int m16 = 0; m16 < 16; ++m16) {
#pragma unroll
    for (int nr = 0; nr < 2; ++nr) {
      int grow = bm * 256 + m16 * 16 + ((lane >> 4) * 4);
      int gcol = bn * 256 + wn * 32 + nr * 16 + frow;
      u16* cp = C + (size_t)grow * N + gcol;
#pragma unroll
      for (int r = 0; r < 4; ++r) cp[(size_t)r * N] = f2bf(acc[m16][nr][r]);
    }
  }
}

// ---------------- 128x128 GEMM (kept for GEMM2): C = A @ B^T ----------------
// OUTMODE 2: f32 partial (split-K over gridDim.z)
template <int OUTMODE>
__global__ __launch_bounds__(256) void gemm_bt(const u16* __restrict__ A,
                                               const u16* __restrict__ B,
                                               void* __restrict__ Cout,
                                               const float* __restrict__ skip,
                                               int M, int N, int K) {
  __shared__ u16 sA[128 * 32];
  __shared__ u16 sB[128 * 32];
  const int tid = threadIdx.x;
  const int lane = tid & 63;
  const int wid = tid >> 6;
  const int wr = wid >> 1, wc = wid & 1;
  const int bm = blockIdx.y, bn = blockIdx.x;
  const int kper = K / gridDim.z;
  const int kbeg = blockIdx.z * kper;

  f32x4 acc[4][4] = {};

  const int srow = tid >> 2;
  const int scol = (tid & 3) << 3;
  const u16* ga = A + (size_t)(bm * 128 + srow) * K + scol;
  const u16* gb = B + (size_t)(bn * 128 + srow) * K + scol;
  u16* la = sA + tid * 8;
  u16* lb = sB + tid * 8;

  const int frow = lane & 15;
  const int kf8 = (lane >> 4) * 8;

  for (int kt = kbeg; kt < kbeg + kper; kt += 32) {
    __syncthreads();
    gld16(la, ga + kt);
    gld16(la + 2048, ga + (size_t)64 * K + kt);
    gld16(lb, gb + kt);
    gld16(lb + 2048, gb + (size_t)64 * K + kt);
    __syncthreads();
    bf16x8 af[4], bfr[4];
#pragma unroll
    for (int m = 0; m < 4; ++m)
      af[m] = *(const bf16x8*)(sA + (wr * 64 + m * 16 + frow) * 32 + kf8);
#pragma unroll
    for (int n = 0; n < 4; ++n)
      bfr[n] = *(const bf16x8*)(sB + (wc * 64 + n * 16 + frow) * 32 + kf8);
#pragma unroll
    for (int m = 0; m < 4; ++m)
#pragma unroll
      for (int n = 0; n < 4; ++n)
        acc[m][n] = __builtin_amdgcn_mfma_f32_16x16x32_bf16(af[m], bfr[n], acc[m][n], 0, 0, 0);
  }

  const int r0 = (lane >> 4) * 4;
  const int c0 = lane & 15;
#pragma unroll
  for (int m = 0; m < 4; ++m) {
#pragma unroll
    for (int n = 0; n < 4; ++n) {
      int grow = bm * 128 + wr * 64 + m * 16 + r0;
      int gcol = bn * 128 + wc * 64 + n * 16 + c0;
      if (OUTMODE == 0) {
        u16* C = (u16*)Cout;
#pragma unroll
        for (int r = 0; r < 4; ++r)
          C[(size_t)(grow + r) * N + gcol] = f2bf(acc[m][n][r]);
      } else if (OUTMODE == 1) {
        float* C = (float*)Cout;
#pragma unroll
        for (int r = 0; r < 4; ++r) {
          size_t idx = (size_t)(grow + r) * N + gcol;
          C[idx] = acc[m][n][r] + skip[idx];
        }
      } else {
        float* C = (float*)Cout + (size_t)blockIdx.z * M * N;
#pragma unroll
        for (int r = 0; r < 4; ++r)
          C[(size_t)(grow + r) * N + gcol] = acc[m][n][r];
      }
    }
  }
}

// ---------------- combine split-K partials + skip ----------------
__global__ __launch_bounds__(256) void combine_kernel(const float* __restrict__ p0,
                                                      const float* __restrict__ p1,
                                                      const float* __restrict__ x,
                                                      float* __restrict__ out, int n4) {
  int i = blockIdx.x * 256 + threadIdx.x;
  if (i < n4) {
    float4 a = ((const float4*)p0)[i];
    float4 b = ((const float4*)p1)[i];
    float4 c = ((const float4*)x)[i];
    float4 o = {a.x + b.x + c.x, a.y + b.y + c.y, a.z + b.z + c.z, a.w + b.w + c.w};
    ((float4*)out)[i] = o;
  }
}

// ---------------- q/k norm + RoPE + v copy ----------------
__global__ __launch_bounds__(256) void qkv_prep(const u16* __restrict__ proj,
                                                const float* __restrict__ theta,
                                                const float* __restrict__ attn_scale,
                                                u16* __restrict__ qb, u16* __restrict__ kb,
                                                u16* __restrict__ vb) {
  const int l = blockIdx.x * 4 + (threadIdx.x >> 6);
  const int hd = blockIdx.y;
  const int e = threadIdx.x & 63;
  const u16* pr = proj + (size_t)l * FPROJ + hd * EHEAD + e;
  float q = bf2f(pr[0]);
  float k = bf2f(pr[DMODEL]);
  float v = bf2f(pr[2 * DMODEL]);
  float sq = q * q, sk = k * k;
#pragma unroll
  for (int m = 1; m < 64; m <<= 1) {
    sq += __shfl_xor(sq, m);
    sk += __shfl_xor(sk, m);
  }
  float s = sqrtf(attn_scale[hd]);
  q *= s * rsqrtf(sq + 1e-6f);
  k *= s * rsqrtf(sk + 1e-6f);
  float ang = theta[((size_t)hd * L_SEQ + l) * 32 + (e & 31)];
  float cs = __cosf(ang), sn = __sinf(ang);
  float qp = __shfl_xor(q, 32), kp = __shfl_xor(k, 32);
  float qr = (e < 32) ? (q * cs - qp * sn) : (q * cs + qp * sn);
  float kr = (e < 32) ? (k * cs - kp * sn) : (k * cs + kp * sn);
  size_t o = ((size_t)hd * L_SEQ + l) * EHEAD + e;
  qb[o] = f2bf(qr);
  kb[o] = f2bf(kr);
  vb[o] = f2bf(v);
}

// ---------------- GELU(up) -> h[:,1024:] ----------------
__global__ __launch_bounds__(256) void gelu_up_kernel(const u16* __restrict__ proj,
                                                      u16* __restrict__ h) {
  int i = blockIdx.x * 256 + threadIdx.x;
  int l = i >> 9;
  int j8 = (i & 511) << 3;
  u16x8 a = *(const u16x8*)(proj + (size_t)l * FPROJ + 3 * DMODEL + j8);
  u16x8 o;
#pragma unroll
  for (int j = 0; j < 8; ++j) {
    float x = bf2f(a[j]);
    float y = 0.7978845608028654f * (x + 0.044715f * x * x * x);
    float t = __expf(-2.0f * fabsf(y));
    float th = (1.0f - t) / (1.0f + t);
    th = (y < 0.0f) ? -th : th;
    o[j] = f2bf(0.5f * x * (1.0f + th));
  }
  *(u16x8*)(h + (size_t)l * FCAT + DMODEL + j8) = o;
}

// ---------------- causal flash attention, 32x32 MFMA, swapped-QK^T ----------------
__global__ __launch_bounds__(128) void attn_kernel(const u16* __restrict__ qb,
                                                   const u16* __restrict__ kb,
                                                   const u16* __restrict__ vb,
                                                   u16* __restrict__ hbuf) {
  const int bid = blockIdx.x;
  const int strip = 31 - (bid >> 4);
  const int hd = bid & 15;
  const int tid = threadIdx.x;
  const int lane = tid & 63;
  const int w = tid >> 6;
  const int h = lane >> 5;
  const int ql = lane & 31;
  const int qg = strip * 64 + w * 32 + ql;

  __shared__ u16 sK[64 * 64];
  __shared__ u16 sVT[64 * 64];

  const u16* Kh = kb + (size_t)hd * L_SEQ * EHEAD;
  const u16* Vh = vb + (size_t)hd * L_SEQ * EHEAD;
  const u16* Qh = qb + (size_t)hd * L_SEQ * EHEAD;

  bf16x8 qf[4];
#pragma unroll
  for (int es = 0; es < 4; ++es)
    qf[es] = *(const bf16x8*)(Qh + (size_t)qg * EHEAD + es * 16 + h * 8);

  f32x16 oa[2] = {};
  float m = NEGINF, lsum = 0.0f;

  const int vk = (tid & 15) * 4;
  const int ve = (tid >> 4) * 8;
  const int ntile = strip + 1;

  for (int kt = 0; kt < ntile; ++kt) {
    const int k0 = kt * 64;
    __syncthreads();
#pragma unroll
    for (int i = 0; i < 4; ++i) {
      int r = w * 32 + i * 8 + (lane >> 3);
      const u16* src = Kh + (size_t)(k0 + r) * EHEAD + (((lane & 7) ^ (r & 7)) << 3);
      gld16(sK + (w * 32 + i * 8) * 64 + lane * 8, src);
    }
    u16x8 vr[4];
#pragma unroll
    for (int j = 0; j < 4; ++j)
      vr[j] = *(const u16x8*)(Vh + (size_t)(k0 + vk + j) * EHEAD + ve);
#pragma unroll
    for (int e = 0; e < 8; ++e) {
      int row = ve + e;
      int boff = row * 128 + ((((vk >> 3) ^ (row & 7)) << 4) | ((vk & 4) << 1));
      ushort4 pv;
      pv.x = vr[0][e]; pv.y = vr[1][e]; pv.z = vr[2][e]; pv.w = vr[3][e];
      *(ushort4*)((char*)sVT + boff) = pv;
    }
    __syncthreads();

    f32x16 st[2];
#pragma unroll
    for (int t = 0; t < 2; ++t) {
      f32x16 a = {};
#pragma unroll
      for (int es = 0; es < 4; ++es) {
        int row = t * 32 + ql;
        int boff = row * 128 + (((es * 2 + h) ^ (row & 7)) << 4);
        bf16x8 kf = *(const bf16x8*)((const char*)sK + boff);
        a = __builtin_amdgcn_mfma_f32_32x32x16_bf16(kf, qf[es], a, 0, 0, 0);
      }
      st[t] = a;
    }

    float p[2][16];
    float mx = NEGINF;
    const bool edge = (kt == strip);
#pragma unroll
    for (int t = 0; t < 2; ++t)
#pragma unroll
      for (int r = 0; r < 16; ++r) {
        float v = st[t][r];
        if (edge) {
          int kg = k0 + t * 32 + (r & 3) + ((r >> 2) << 3) + h * 4;
          v = (kg > qg) ? NEGINF : v;
        }
        p[t][r] = v;
        mx = fmaxf(mx, v);
      }
    mx = fmaxf(mx, __shfl_xor(mx, 32));
    float mnew = fmaxf(m, mx);
    float alpha = __expf(m - mnew);
    float ps = 0.0f;
#pragma unroll
    for (int t = 0; t < 2; ++t)
#pragma unroll
      for (int r = 0; r < 16; ++r) {
        float e_ = __expf(p[t][r] - mnew);
        p[t][r] = e_;
        ps += e_;
      }
    ps += __shfl_xor(ps, 32);
    lsum = lsum * alpha + ps;
    m = mnew;
#pragma unroll
    for (int et = 0; et < 2; ++et)
#pragma unroll
      for (int r = 0; r < 16; ++r) oa[et][r] *= alpha;

    u32 pk_[2][8];
#pragma unroll
    for (int t = 0; t < 2; ++t)
#pragma unroll
      for (int i = 0; i < 8; ++i)
        pk_[t][i] = (u32)f2bf(p[t][2 * i]) | ((u32)f2bf(p[t][2 * i + 1]) << 16);

#pragma unroll
    for (int ks = 0; ks < 4; ++ks) {
      const int tp = ks >> 1, base = (ks & 1) * 4;
      u32 s0 = h ? pk_[tp][base + 0] : pk_[tp][base + 2];
      u32 s1 = h ? pk_[tp][base + 1] : pk_[tp][base + 3];
      u32 r0 = (u32)__shfl_xor((int)s0, 32);
      u32 r1 = (u32)__shfl_xor((int)s1, 32);
      union { u32 u[4]; bf16x8 v; } pf;
      pf.u[0] = h ? r0 : pk_[tp][base + 0];
      pf.u[1] = h ? r1 : pk_[tp][base + 1];
      pf.u[2] = h ? pk_[tp][base + 2] : r0;
      pf.u[3] = h ? pk_[tp][base + 3] : r1;
#pragma unroll
      for (int et = 0; et < 2; ++et) {
        int row = et * 32 + ql;
        int boff = row * 128 + (((ks * 2 + h) ^ (row & 7)) << 4);
        bf16x8 vf = *(const bf16x8*)((const char*)sVT + boff);
        oa[et] = __builtin_amdgcn_mfma_f32_32x32x16_bf16(vf, pf.v, oa[et], 0, 0, 0);
      }
    }
  }

  float rdiv = 1.0f / lsum;
  u16* orow = hbuf + (size_t)qg * FCAT + hd * EHEAD;
#pragma unroll
  for (int et = 0; et < 2; ++et)
#pragma unroll
    for (int g = 0; g < 4; ++g) {
      ushort4 ov;
      ov.x = f2bf(oa[et][4 * g + 0] * rdiv);
      ov.y = f2bf(oa[et][4 * g + 1] * rdiv);
      ov.z = f2bf(oa[et][4 * g + 2] * rdiv);
      ov.w = f2bf(oa[et][4 * g + 3] * rdiv);
      *(ushort4*)(orow + et * 32 + g * 8 + h * 4) = ov;
    }
}

extern "C" void kernel_launch(void* const* d_in, const int* in_sizes, int n_in,
                              void* d_out, int out_size, void* d_ws, size_t ws_size,
                              hipStream_t stream) {
  const float* x = (const float*)d_in[0];
  const float* theta = (const float*)d_in[1];
  const float* scale = (const float*)d_in[2];
  const float* w_in = (const float*)d_in[3];
  const float* w_out = (const float*)d_in[4];
  const float* attn_scale = (const float*)d_in[5];
  float* out = (float*)d_out;

  char* ws = (char*)d_ws;
  u16* xn = (u16*)ws;        ws += (size_t)L_SEQ * DMODEL * 2;
  u16* w_in_b = (u16*)ws;    ws += (size_t)FPROJ * DMODEL * 2;
  u16* w_out_b = (u16*)ws;   ws += (size_t)DMODEL * FCAT * 2;
  u16* proj = (u16*)ws;      ws += (size_t)L_SEQ * FPROJ * 2;
  u16* qb = (u16*)ws;        ws += (size_t)NHEAD * L_SEQ * EHEAD * 2;
  u16* kb = (u16*)ws;        ws += (size_t)NHEAD * L_SEQ * EHEAD * 2;
  u16* vb = (u16*)ws;        ws += (size_t)NHEAD * L_SEQ * EHEAD * 2;
  u16* hb = (u16*)ws;        ws += (size_t)L_SEQ * FCAT * 2;
  float* part = (float*)proj;  // reuse: proj's last reader precedes gemm2

  cvt_kernel<<<7168, 256, 0, stream>>>(w_in, w_in_b, FPROJ * DMODEL / 4);
  cvt_kernel<<<5120, 256, 0, stream>>>(w_out, w_out_b, DMODEL * FCAT / 4);
  rmsnorm_kernel<<<L_SEQ, 256, 0, stream>>>(x, scale, xn);
  gemm256<<<(L_SEQ / 256) * (FPROJ / 256), 512, 0, stream>>>(xn, w_in_b, proj,
                                                             L_SEQ, FPROJ, DMODEL);
  qkv_prep<<<dim3(L_SEQ / 4, NHEAD), 256, 0, stream>>>(proj, theta, attn_scale, qb, kb, vb);
  gelu_up_kernel<<<L_SEQ * 512 / 256, 256, 0, stream>>>(proj, hb);
  attn_kernel<<<512, 128, 0, stream>>>(qb, kb, vb, hb);
  gemm_bt<2><<<dim3(DMODEL / 128, L_SEQ / 128, 2), 256, 0, stream>>>(hb, w_out_b, part, nullptr,
                                                                     L_SEQ, DMODEL, FCAT);
  combine_kernel<<<L_SEQ * DMODEL / 4 / 256, 256, 0, stream>>>(part, part + (size_t)L_SEQ * DMODEL,
                                                               x, out, L_SEQ * DMODEL / 4);
}

// Round 5
// 171.363 us; speedup vs baseline: 1.8291x; 1.2063x over previous
//
#include <hip/hip_runtime.h>

typedef unsigned short u16;
typedef unsigned int u32;
typedef __attribute__((ext_vector_type(8))) short bf16x8;
typedef __attribute__((ext_vector_type(8))) unsigned short u16x8;
typedef __attribute__((ext_vector_type(4))) float f32x4;
typedef __attribute__((ext_vector_type(16))) float f32x16;

#define L_SEQ 2048
#define DMODEL 1024
#define NHEAD 16
#define EHEAD 64
#define FPROJ 7168
#define FCAT 5120
#define NEGINF -1e30f

__device__ __forceinline__ u16 f2bf(float f) {
  union { float f; u32 u; } v; v.f = f;
  u32 r = v.u + 0x7FFFu + ((v.u >> 16) & 1u);
  return (u16)(r >> 16);
}
__device__ __forceinline__ float bf2f(u16 h) {
  union { u32 u; float f; } v; v.u = ((u32)h) << 16;
  return v.f;
}
__device__ __forceinline__ float gelu_f(float x) {
  float y = 0.7978845608028654f * (x + 0.044715f * x * x * x);
  float t = __expf(-2.0f * fabsf(y));
  float th = (1.0f - t) / (1.0f + t);
  th = (y < 0.0f) ? -th : th;
  return 0.5f * x * (1.0f + th);
}
__device__ __forceinline__ void gld16(void* lds, const void* g) {
  __builtin_amdgcn_global_load_lds((const __attribute__((address_space(1))) u32*)g,
                                   (__attribute__((address_space(3))) u32*)lds, 16, 0, 0);
}

// ---------------- f32 -> bf16 convert (weights) ----------------
__global__ __launch_bounds__(256) void cvt_kernel(const float* __restrict__ in,
                                                  u16* __restrict__ out, int n4) {
  int i = blockIdx.x * 256 + threadIdx.x;
  if (i < n4) {
    float4 a = ((const float4*)in)[i];
    u16 o0 = f2bf(a.x), o1 = f2bf(a.y), o2 = f2bf(a.z), o3 = f2bf(a.w);
    ((u32*)out)[2 * i] = (u32)o0 | ((u32)o1 << 16);
    ((u32*)out)[2 * i + 1] = (u32)o2 | ((u32)o3 << 16);
  }
}

// ---------------- RMSNorm * (1+scale) -> bf16 ----------------
__global__ __launch_bounds__(256) void rmsnorm_kernel(const float* __restrict__ x,
                                                      const float* __restrict__ scale,
                                                      u16* __restrict__ xn) {
  int row = blockIdx.x;
  const float4 v = ((const float4*)(x + (size_t)row * DMODEL))[threadIdx.x];
  float ss = v.x * v.x + v.y * v.y + v.z * v.z + v.w * v.w;
#pragma unroll
  for (int m = 1; m < 64; m <<= 1) ss += __shfl_xor(ss, m);
  __shared__ float ws[4];
  if ((threadIdx.x & 63) == 0) ws[threadIdx.x >> 6] = ss;
  __syncthreads();
  float tot = ws[0] + ws[1] + ws[2] + ws[3];
  float r = rsqrtf(tot * (1.0f / DMODEL) + 1e-6f);
  float4 sc = ((const float4*)scale)[threadIdx.x];
  u32 w0 = (u32)f2bf(v.x * r * (1.0f + sc.x)) | ((u32)f2bf(v.y * r * (1.0f + sc.y)) << 16);
  u32 w1 = (u32)f2bf(v.z * r * (1.0f + sc.z)) | ((u32)f2bf(v.w * r * (1.0f + sc.w)) << 16);
  u32* dst = (u32*)(xn + (size_t)row * DMODEL);
  dst[2 * threadIdx.x] = w0;
  dst[2 * threadIdx.x + 1] = w1;
}

// ---------------- 256x256 8-phase GEMM: C(M,N) = A(M,K) @ B(N,K)^T ----------------
// 512 threads = 8 waves (1M x 8N). BK=64, 2 K-tiles per 8-phase iteration.
// XOR-swizzled LDS via pre-swizzled global src (linear gld_lds dest); counted
// vmcnt(2) at phases 4/8 only; raw s_barrier; setprio around MFMA clusters.
// Split-K over gridDim.y (kper = K/gridDim.y).
// OUTMODE 1 (GEMM1): cols<3072 -> bf16 proj (ld 3072); cols>=3072 -> gelu -> hb (ld FCAT, -2048).
// OUTMODE 2 (GEMM2): bf16 partial per split at C0 + blockIdx.y*M*N.
__device__ __forceinline__ void stage_half(u16* lds, const u16* g, int K, int tid) {
#pragma unroll
  for (int i = 0; i < 2; ++i) {
    int idx = tid + i * 512;                      // 0..1023 chunk of 16B
    int r = idx >> 3;                             // row 0..127
    int gcb = ((idx & 7) << 4) ^ ((r & 7) << 4);  // inverse-swizzled col byte
    gld16((char*)lds + idx * 16, (const char*)g + (size_t)r * K * 2 + gcb);
  }
}

#define GFENCE asm volatile("" ::: "memory")
#define VMW2 asm volatile("s_waitcnt vmcnt(2)" ::: "memory")
#define ST_A(BUF, T, HALF) stage_half(sA + (BUF) * 16384 + (HALF) * 8192, \
    Ab + (size_t)((HALF) * 128) * K + (T) * 64, K, tid)
#define ST_B(BUF, T, HALF) stage_half(sB + (BUF) * 16384 + (HALF) * 8192, \
    Bb + (size_t)((HALF) * 128) * K + (T) * 64, K, tid)

#define PHASE(HM, KH, BUFB, DOVM, STCODE) do { \
    const char* ab_ = (const char*)sA + (BUFB) * 32768 + (HM) * 16384 + frow * 128 + ((KH) ? co1 : co0); \
    const char* bb_ = (const char*)sB + (BUFB) * 32768 + (wn * 32 + frow) * 128 + ((KH) ? co1 : co0); \
    bf16x8 af_[8], bv_[2]; \
    _Pragma("unroll") \
    for (int mr = 0; mr < 8; ++mr) af_[mr] = *(const bf16x8*)(ab_ + mr * 2048); \
    bv_[0] = *(const bf16x8*)(bb_); \
    bv_[1] = *(const bf16x8*)(bb_ + 2048); \
    GFENCE; \
    STCODE; \
    if (DOVM) VMW2; \
    __builtin_amdgcn_s_barrier(); \
    __builtin_amdgcn_s_setprio(1); \
    _Pragma("unroll") \
    for (int mr = 0; mr < 8; ++mr) { \
      acc[(HM) * 8 + mr][0] = __builtin_amdgcn_mfma_f32_16x16x32_bf16(af_[mr], bv_[0], acc[(HM) * 8 + mr][0], 0, 0, 0); \
      acc[(HM) * 8 + mr][1] = __builtin_amdgcn_mfma_f32_16x16x32_bf16(af_[mr], bv_[1], acc[(HM) * 8 + mr][1], 0, 0, 0); \
    } \
    __builtin_amdgcn_s_setprio(0); \
    __builtin_amdgcn_s_barrier(); \
  } while (0)

template <int OUTMODE>
__global__ __launch_bounds__(512, 2) void gemm256(const u16* __restrict__ A,
                                                  const u16* __restrict__ B,
                                                  u16* __restrict__ C0,
                                                  u16* __restrict__ C1,
                                                  int M, int N, int K) {
  __shared__ __align__(16) u16 sA[2 * 16384];
  __shared__ __align__(16) u16 sB[2 * 16384];
  const int tid = threadIdx.x;
  const int lane = tid & 63;
  const int wn = tid >> 6;
  const int frow = lane & 15;
  const int kbyte = ((lane >> 4) & 3) << 4;
  const int sw = (frow & 7) << 4;
  const int co0 = kbyte ^ sw;
  const int co1 = (64 | kbyte) ^ sw;

  const int nbx = N >> 8;
  const int v = (blockIdx.x & 7) * ((int)gridDim.x >> 3) + ((int)blockIdx.x >> 3);
  const int bm = v / nbx, bn = v % nbx;
  const int kper = K / (int)gridDim.y;
  const int kbeg = blockIdx.y * kper;
  const u16* Ab = A + (size_t)(bm * 256) * K + kbeg;
  const u16* Bb = B + (size_t)(bn * 256) * K + kbeg;

  f32x4 acc[16][2] = {};

  const int NT = kper >> 6;
  // prologue: tile0 {A0, B.h0, B.h1, A1}, tile1 {A0}
  ST_A(0, 0, 0); ST_B(0, 0, 0); ST_B(0, 0, 1); ST_A(0, 0, 1); ST_A(1, 1, 0);
  VMW2;
  __builtin_amdgcn_s_barrier();

  for (int kt = 0; kt < NT; kt += 2) {
    const int t1 = kt + 1;
    const int t2 = (kt + 2 >= NT) ? kt + 2 - NT : kt + 2;
    const int t3 = (kt + 3 >= NT) ? kt + 3 - NT : kt + 3;
    PHASE(0, 0, 0, 0, ST_B(1, t1, 0));
    PHASE(0, 1, 0, 0, ST_B(1, t1, 1));
    PHASE(1, 0, 0, 0, ST_A(1, t1, 1));
    PHASE(1, 1, 0, 1, ST_A(0, t2, 0));
    PHASE(0, 0, 1, 0, ST_B(0, t2, 0));
    PHASE(0, 1, 1, 0, ST_B(0, t2, 1));
    PHASE(1, 0, 1, 0, ST_A(0, t2, 1));
    PHASE(1, 1, 1, 1, ST_A(1, t3, 0));
  }

  if (OUTMODE == 1) {
    const bool up = (bn >= 12);  // cols >= 3*DMODEL
#pragma unroll
    for (int m16 = 0; m16 < 16; ++m16) {
#pragma unroll
      for (int nr = 0; nr < 2; ++nr) {
        int grow = bm * 256 + m16 * 16 + ((lane >> 4) * 4);
        int gcol = bn * 256 + wn * 32 + nr * 16 + frow;
        if (!up) {
          u16* cp = C0 + (size_t)grow * (3 * DMODEL) + gcol;
#pragma unroll
          for (int r = 0; r < 4; ++r) cp[(size_t)r * (3 * DMODEL)] = f2bf(acc[m16][nr][r]);
        } else {
          u16* cp = C1 + (size_t)grow * FCAT + (gcol - 2048);
#pragma unroll
          for (int r = 0; r < 4; ++r) cp[(size_t)r * FCAT] = f2bf(gelu_f(acc[m16][nr][r]));
        }
      }
    }
  } else {
    u16* Cp = C0 + (size_t)blockIdx.y * M * N;
#pragma unroll
    for (int m16 = 0; m16 < 16; ++m16) {
#pragma unroll
      for (int nr = 0; nr < 2; ++nr) {
        int grow = bm * 256 + m16 * 16 + ((lane >> 4) * 4);
        int gcol = bn * 256 + wn * 32 + nr * 16 + frow;
        u16* cp = Cp + (size_t)grow * N + gcol;
#pragma unroll
        for (int r = 0; r < 4; ++r) cp[(size_t)r * N] = f2bf(acc[m16][nr][r]);
      }
    }
  }
}

// ---------------- combine 8 bf16 split-K partials + skip -> f32 out ----------------
__global__ __launch_bounds__(256) void combine8(const u16* __restrict__ part,
                                                const float* __restrict__ x,
                                                float* __restrict__ out) {
  size_t i = (size_t)(blockIdx.x * 256 + threadIdx.x) * 8;
  float4 x0 = *(const float4*)(x + i);
  float4 x1 = *(const float4*)(x + i + 4);
  float s[8] = {x0.x, x0.y, x0.z, x0.w, x1.x, x1.y, x1.z, x1.w};
#pragma unroll
  for (int p = 0; p < 8; ++p) {
    u16x8 v = *(const u16x8*)(part + (size_t)p * (L_SEQ * DMODEL) + i);
#pragma unroll
    for (int j = 0; j < 8; ++j) s[j] += bf2f(v[j]);
  }
  float4 o0 = {s[0], s[1], s[2], s[3]};
  float4 o1 = {s[4], s[5], s[6], s[7]};
  *(float4*)(out + i) = o0;
  *(float4*)(out + i + 4) = o1;
}

// ---------------- q/k norm + RoPE + v copy (proj stride 3072) ----------------
__global__ __launch_bounds__(256) void qkv_prep(const u16* __restrict__ proj,
                                                const float* __restrict__ theta,
                                                const float* __restrict__ attn_scale,
                                                u16* __restrict__ qb, u16* __restrict__ kb,
                                                u16* __restrict__ vb) {
  const int l = blockIdx.x * 4 + (threadIdx.x >> 6);
  const int hd = blockIdx.y;
  const int e = threadIdx.x & 63;
  const u16* pr = proj + (size_t)l * (3 * DMODEL) + hd * EHEAD + e;
  float q = bf2f(pr[0]);
  float k = bf2f(pr[DMODEL]);
  float v = bf2f(pr[2 * DMODEL]);
  float sq = q * q, sk = k * k;
#pragma unroll
  for (int m = 1; m < 64; m <<= 1) {
    sq += __shfl_xor(sq, m);
    sk += __shfl_xor(sk, m);
  }
  float s = sqrtf(attn_scale[hd]);
  q *= s * rsqrtf(sq + 1e-6f);
  k *= s * rsqrtf(sk + 1e-6f);
  float ang = theta[((size_t)hd * L_SEQ + l) * 32 + (e & 31)];
  float cs = __cosf(ang), sn = __sinf(ang);
  float qp = __shfl_xor(q, 32), kp = __shfl_xor(k, 32);
  float qr = (e < 32) ? (q * cs - qp * sn) : (q * cs + qp * sn);
  float kr = (e < 32) ? (k * cs - kp * sn) : (k * cs + kp * sn);
  size_t o = ((size_t)hd * L_SEQ + l) * EHEAD + e;
  qb[o] = f2bf(qr);
  kb[o] = f2bf(kr);
  vb[o] = f2bf(v);
}

// ---------------- causal flash attention, 32x32 MFMA, swapped-QK^T ----------------
__global__ __launch_bounds__(128) void attn_kernel(const u16* __restrict__ qb,
                                                   const u16* __restrict__ kb,
                                                   const u16* __restrict__ vb,
                                                   u16* __restrict__ hbuf) {
  const int bid = blockIdx.x;
  const int strip = 31 - (bid >> 4);
  const int hd = bid & 15;
  const int tid = threadIdx.x;
  const int lane = tid & 63;
  const int w = tid >> 6;
  const int h = lane >> 5;
  const int ql = lane & 31;
  const int qg = strip * 64 + w * 32 + ql;

  __shared__ u16 sK[64 * 64];
  __shared__ u16 sVT[64 * 64];

  const u16* Kh = kb + (size_t)hd * L_SEQ * EHEAD;
  const u16* Vh = vb + (size_t)hd * L_SEQ * EHEAD;
  const u16* Qh = qb + (size_t)hd * L_SEQ * EHEAD;

  bf16x8 qf[4];
#pragma unroll
  for (int es = 0; es < 4; ++es)
    qf[es] = *(const bf16x8*)(Qh + (size_t)qg * EHEAD + es * 16 + h * 8);

  f32x16 oa[2] = {};
  float m = NEGINF, lsum = 0.0f;

  const int vk = (tid & 15) * 4;
  const int ve = (tid >> 4) * 8;
  const int ntile = strip + 1;

  for (int kt = 0; kt < ntile; ++kt) {
    const int k0 = kt * 64;
    __syncthreads();
#pragma unroll
    for (int i = 0; i < 4; ++i) {
      int r = w * 32 + i * 8 + (lane >> 3);
      const u16* src = Kh + (size_t)(k0 + r) * EHEAD + (((lane & 7) ^ (r & 7)) << 3);
      gld16(sK + (w * 32 + i * 8) * 64 + lane * 8, src);
    }
    u16x8 vr[4];
#pragma unroll
    for (int j = 0; j < 4; ++j)
      vr[j] = *(const u16x8*)(Vh + (size_t)(k0 + vk + j) * EHEAD + ve);
#pragma unroll
    for (int e = 0; e < 8; ++e) {
      int row = ve + e;
      int boff = row * 128 + ((((vk >> 3) ^ (row & 7)) << 4) | ((vk & 4) << 1));
      ushort4 pv;
      pv.x = vr[0][e]; pv.y = vr[1][e]; pv.z = vr[2][e]; pv.w = vr[3][e];
      *(ushort4*)((char*)sVT + boff) = pv;
    }
    __syncthreads();

    f32x16 st[2];
#pragma unroll
    for (int t = 0; t < 2; ++t) {
      f32x16 a = {};
#pragma unroll
      for (int es = 0; es < 4; ++es) {
        int row = t * 32 + ql;
        int boff = row * 128 + (((es * 2 + h) ^ (row & 7)) << 4);
        bf16x8 kf = *(const bf16x8*)((const char*)sK + boff);
        a = __builtin_amdgcn_mfma_f32_32x32x16_bf16(kf, qf[es], a, 0, 0, 0);
      }
      st[t] = a;
    }

    float p[2][16];
    float mx = NEGINF;
    const bool edge = (kt == strip);
#pragma unroll
    for (int t = 0; t < 2; ++t)
#pragma unroll
      for (int r = 0; r < 16; ++r) {
        float v = st[t][r];
        if (edge) {
          int kg = k0 + t * 32 + (r & 3) + ((r >> 2) << 3) + h * 4;
          v = (kg > qg) ? NEGINF : v;
        }
        p[t][r] = v;
        mx = fmaxf(mx, v);
      }
    mx = fmaxf(mx, __shfl_xor(mx, 32));
    float mnew = fmaxf(m, mx);
    float alpha = __expf(m - mnew);
    float ps = 0.0f;
#pragma unroll
    for (int t = 0; t < 2; ++t)
#pragma unroll
      for (int r = 0; r < 16; ++r) {
        float e_ = __expf(p[t][r] - mnew);
        p[t][r] = e_;
        ps += e_;
      }
    ps += __shfl_xor(ps, 32);
    lsum = lsum * alpha + ps;
    m = mnew;
#pragma unroll
    for (int et = 0; et < 2; ++et)
#pragma unroll
      for (int r = 0; r < 16; ++r) oa[et][r] *= alpha;

    u32 pk_[2][8];
#pragma unroll
    for (int t = 0; t < 2; ++t)
#pragma unroll
      for (int i = 0; i < 8; ++i)
        pk_[t][i] = (u32)f2bf(p[t][2 * i]) | ((u32)f2bf(p[t][2 * i + 1]) << 16);

#pragma unroll
    for (int ks = 0; ks < 4; ++ks) {
      const int tp = ks >> 1, base = (ks & 1) * 4;
      u32 s0 = h ? pk_[tp][base + 0] : pk_[tp][base + 2];
      u32 s1 = h ? pk_[tp][base + 1] : pk_[tp][base + 3];
      u32 r0 = (u32)__shfl_xor((int)s0, 32);
      u32 r1 = (u32)__shfl_xor((int)s1, 32);
      union { u32 u[4]; bf16x8 v; } pf;
      pf.u[0] = h ? r0 : pk_[tp][base + 0];
      pf.u[1] = h ? r1 : pk_[tp][base + 1];
      pf.u[2] = h ? pk_[tp][base + 2] : r0;
      pf.u[3] = h ? pk_[tp][base + 3] : r1;
#pragma unroll
      for (int et = 0; et < 2; ++et) {
        int row = et * 32 + ql;
        int boff = row * 128 + (((ks * 2 + h) ^ (row & 7)) << 4);
        bf16x8 vf = *(const bf16x8*)((const char*)sVT + boff);
        oa[et] = __builtin_amdgcn_mfma_f32_32x32x16_bf16(vf, pf.v, oa[et], 0, 0, 0);
      }
    }
  }

  float rdiv = 1.0f / lsum;
  u16* orow = hbuf + (size_t)qg * FCAT + hd * EHEAD;
#pragma unroll
  for (int et = 0; et < 2; ++et)
#pragma unroll
    for (int g = 0; g < 4; ++g) {
      ushort4 ov;
      ov.x = f2bf(oa[et][4 * g + 0] * rdiv);
      ov.y = f2bf(oa[et][4 * g + 1] * rdiv);
      ov.z = f2bf(oa[et][4 * g + 2] * rdiv);
      ov.w = f2bf(oa[et][4 * g + 3] * rdiv);
      *(ushort4*)(orow + et * 32 + g * 8 + h * 4) = ov;
    }
}

extern "C" void kernel_launch(void* const* d_in, const int* in_sizes, int n_in,
                              void* d_out, int out_size, void* d_ws, size_t ws_size,
                              hipStream_t stream) {
  const float* x = (const float*)d_in[0];
  const float* theta = (const float*)d_in[1];
  const float* scale = (const float*)d_in[2];
  const float* w_in = (const float*)d_in[3];
  const float* w_out = (const float*)d_in[4];
  const float* attn_scale = (const float*)d_in[5];
  float* out = (float*)d_out;

  // ws layout: live-at-GEMM2 buffers first; dead-by-GEMM2 region [xn|w_in_b|proj|qb...]
  // is contiguous and overlaid by the 33.5MB bf16 split-K partials.
  char* ws = (char*)d_ws;
  u16* w_out_b = (u16*)ws;   ws += (size_t)DMODEL * FCAT * 2;        // live: GEMM2 B
  u16* hb = (u16*)ws;        ws += (size_t)L_SEQ * FCAT * 2;         // live: GEMM2 A
  u16* xn = (u16*)ws;        ws += (size_t)L_SEQ * DMODEL * 2;       // dead after GEMM1
  u16* w_in_b = (u16*)ws;    ws += (size_t)FPROJ * DMODEL * 2;       // dead after GEMM1
  u16* proj = (u16*)ws;      ws += (size_t)L_SEQ * 3 * DMODEL * 2;   // dead after qkv_prep
  u16* qb = (u16*)ws;        ws += (size_t)NHEAD * L_SEQ * EHEAD * 2;  // dead after attn
  u16* kb = (u16*)ws;        ws += (size_t)NHEAD * L_SEQ * EHEAD * 2;
  u16* vb = (u16*)ws;        ws += (size_t)NHEAD * L_SEQ * EHEAD * 2;
  u16* part = xn;  // 8 * L_SEQ*DMODEL bf16 = 33.5MB, fits xn..qb (35.7MB)

  cvt_kernel<<<7168, 256, 0, stream>>>(w_in, w_in_b, FPROJ * DMODEL / 4);
  cvt_kernel<<<5120, 256, 0, stream>>>(w_out, w_out_b, DMODEL * FCAT / 4);
  rmsnorm_kernel<<<L_SEQ, 256, 0, stream>>>(x, scale, xn);
  gemm256<1><<<(L_SEQ / 256) * (FPROJ / 256), 512, 0, stream>>>(xn, w_in_b, proj, hb,
                                                                L_SEQ, FPROJ, DMODEL);
  qkv_prep<<<dim3(L_SEQ / 4, NHEAD), 256, 0, stream>>>(proj, theta, attn_scale, qb, kb, vb);
  attn_kernel<<<512, 128, 0, stream>>>(qb, kb, vb, hb);
  gemm256<2><<<dim3((L_SEQ / 256) * (DMODEL / 256), 8), 512, 0, stream>>>(hb, w_out_b, part,
                                                                          nullptr, L_SEQ, DMODEL, FCAT);
  combine8<<<L_SEQ * DMODEL / 8 / 256, 256, 0, stream>>>(part, x, out);
}

// Round 7
// 144.555 us; speedup vs baseline: 2.1683x; 1.1855x over previous
//
#include <hip/hip_runtime.h>

typedef unsigned short u16;
typedef unsigned int u32;
typedef __attribute__((ext_vector_type(8))) short bf16x8;
typedef __attribute__((ext_vector_type(8))) unsigned short u16x8;
typedef __attribute__((ext_vector_type(4))) float f32x4;
typedef __attribute__((ext_vector_type(16))) float f32x16;

#define L_SEQ 2048
#define DMODEL 1024
#define NHEAD 16
#define EHEAD 64
#define FPROJ 7168
#define FCAT 5120
#define NEGINF -1e30f
#define LOG2E 1.44269504088896f
#define EXP2F(x) __builtin_amdgcn_exp2f(x)

__device__ __forceinline__ u16 f2bf(float f) {
  union { float f; u32 u; } v; v.f = f;
  u32 r = v.u + 0x7FFFu + ((v.u >> 16) & 1u);
  return (u16)(r >> 16);
}
__device__ __forceinline__ float bf2f(u16 h) {
  union { u32 u; float f; } v; v.u = ((u32)h) << 16;
  return v.f;
}
__device__ __forceinline__ float gelu_f(float x) {
  float y = 0.7978845608028654f * (x + 0.044715f * x * x * x);
  float t = __expf(-2.0f * fabsf(y));
  float th = (1.0f - t) / (1.0f + t);
  th = (y < 0.0f) ? -th : th;
  return 0.5f * x * (1.0f + th);
}
__device__ __forceinline__ void gld16(void* lds, const void* g) {
  __builtin_amdgcn_global_load_lds((const __attribute__((address_space(1))) u32*)g,
                                   (__attribute__((address_space(3))) u32*)lds, 16, 0, 0);
}

// ---------------- f32 -> bf16 convert (weights) ----------------
__global__ __launch_bounds__(256) void cvt_kernel(const float* __restrict__ in,
                                                  u16* __restrict__ out, int n4) {
  int i = blockIdx.x * 256 + threadIdx.x;
  if (i < n4) {
    float4 a = ((const float4*)in)[i];
    u16 o0 = f2bf(a.x), o1 = f2bf(a.y), o2 = f2bf(a.z), o3 = f2bf(a.w);
    ((u32*)out)[2 * i] = (u32)o0 | ((u32)o1 << 16);
    ((u32*)out)[2 * i + 1] = (u32)o2 | ((u32)o3 << 16);
  }
}

// ---------------- RMSNorm * (1+scale) -> bf16 ----------------
__global__ __launch_bounds__(256) void rmsnorm_kernel(const float* __restrict__ x,
                                                      const float* __restrict__ scale,
                                                      u16* __restrict__ xn) {
  int row = blockIdx.x;
  const float4 v = ((const float4*)(x + (size_t)row * DMODEL))[threadIdx.x];
  float ss = v.x * v.x + v.y * v.y + v.z * v.z + v.w * v.w;
#pragma unroll
  for (int m = 1; m < 64; m <<= 1) ss += __shfl_xor(ss, m);
  __shared__ float ws[4];
  if ((threadIdx.x & 63) == 0) ws[threadIdx.x >> 6] = ss;
  __syncthreads();
  float tot = ws[0] + ws[1] + ws[2] + ws[3];
  float r = rsqrtf(tot * (1.0f / DMODEL) + 1e-6f);
  float4 sc = ((const float4*)scale)[threadIdx.x];
  u32 w0 = (u32)f2bf(v.x * r * (1.0f + sc.x)) | ((u32)f2bf(v.y * r * (1.0f + sc.y)) << 16);
  u32 w1 = (u32)f2bf(v.z * r * (1.0f + sc.z)) | ((u32)f2bf(v.w * r * (1.0f + sc.w)) << 16);
  u32* dst = (u32*)(xn + (size_t)row * DMODEL);
  dst[2 * threadIdx.x] = w0;
  dst[2 * threadIdx.x + 1] = w1;
}

// ---------------- 256x256 8-phase GEMM (see round 4 notes) ----------------
__device__ __forceinline__ void stage_half(u16* lds, const u16* g, int K, int tid) {
#pragma unroll
  for (int i = 0; i < 2; ++i) {
    int idx = tid + i * 512;
    int r = idx >> 3;
    int gcb = ((idx & 7) << 4) ^ ((r & 7) << 4);
    gld16((char*)lds + idx * 16, (const char*)g + (size_t)r * K * 2 + gcb);
  }
}

#define GFENCE asm volatile("" ::: "memory")
#define VMW2 asm volatile("s_waitcnt vmcnt(2)" ::: "memory")
#define ST_A(BUF, T, HALF) stage_half(sA + (BUF) * 16384 + (HALF) * 8192, \
    Ab + (size_t)((HALF) * 128) * K + (T) * 64, K, tid)
#define ST_B(BUF, T, HALF) stage_half(sB + (BUF) * 16384 + (HALF) * 8192, \
    Bb + (size_t)((HALF) * 128) * K + (T) * 64, K, tid)

#define PHASE(HM, KH, BUFB, DOVM, STCODE) do { \
    const char* ab_ = (const char*)sA + (BUFB) * 32768 + (HM) * 16384 + frow * 128 + ((KH) ? co1 : co0); \
    const char* bb_ = (const char*)sB + (BUFB) * 32768 + (wn * 32 + frow) * 128 + ((KH) ? co1 : co0); \
    bf16x8 af_[8], bv_[2]; \
    _Pragma("unroll") \
    for (int mr = 0; mr < 8; ++mr) af_[mr] = *(const bf16x8*)(ab_ + mr * 2048); \
    bv_[0] = *(const bf16x8*)(bb_); \
    bv_[1] = *(const bf16x8*)(bb_ + 2048); \
    GFENCE; \
    STCODE; \
    if (DOVM) VMW2; \
    __builtin_amdgcn_s_barrier(); \
    __builtin_amdgcn_s_setprio(1); \
    _Pragma("unroll") \
    for (int mr = 0; mr < 8; ++mr) { \
      acc[(HM) * 8 + mr][0] = __builtin_amdgcn_mfma_f32_16x16x32_bf16(af_[mr], bv_[0], acc[(HM) * 8 + mr][0], 0, 0, 0); \
      acc[(HM) * 8 + mr][1] = __builtin_amdgcn_mfma_f32_16x16x32_bf16(af_[mr], bv_[1], acc[(HM) * 8 + mr][1], 0, 0, 0); \
    } \
    __builtin_amdgcn_s_setprio(0); \
    __builtin_amdgcn_s_barrier(); \
  } while (0)

template <int OUTMODE>
__global__ __launch_bounds__(512, 2) void gemm256(const u16* __restrict__ A,
                                                  const u16* __restrict__ B,
                                                  u16* __restrict__ C0,
                                                  u16* __restrict__ C1,
                                                  int M, int N, int K) {
  __shared__ __align__(16) u16 sA[2 * 16384];
  __shared__ __align__(16) u16 sB[2 * 16384];
  const int tid = threadIdx.x;
  const int lane = tid & 63;
  const int wn = tid >> 6;
  const int frow = lane & 15;
  const int kbyte = ((lane >> 4) & 3) << 4;
  const int sw = (frow & 7) << 4;
  const int co0 = kbyte ^ sw;
  const int co1 = (64 | kbyte) ^ sw;

  const int nbx = N >> 8;
  const int v = (blockIdx.x & 7) * ((int)gridDim.x >> 3) + ((int)blockIdx.x >> 3);
  const int bm = v / nbx, bn = v % nbx;
  const int kper = K / (int)gridDim.y;
  const int kbeg = blockIdx.y * kper;
  const u16* Ab = A + (size_t)(bm * 256) * K + kbeg;
  const u16* Bb = B + (size_t)(bn * 256) * K + kbeg;

  f32x4 acc[16][2] = {};

  const int NT = kper >> 6;
  ST_A(0, 0, 0); ST_B(0, 0, 0); ST_B(0, 0, 1); ST_A(0, 0, 1); ST_A(1, 1, 0);
  VMW2;
  __builtin_amdgcn_s_barrier();

  for (int kt = 0; kt < NT; kt += 2) {
    const int t1 = kt + 1;
    const int t2 = (kt + 2 >= NT) ? kt + 2 - NT : kt + 2;
    const int t3 = (kt + 3 >= NT) ? kt + 3 - NT : kt + 3;
    PHASE(0, 0, 0, 0, ST_B(1, t1, 0));
    PHASE(0, 1, 0, 0, ST_B(1, t1, 1));
    PHASE(1, 0, 0, 0, ST_A(1, t1, 1));
    PHASE(1, 1, 0, 1, ST_A(0, t2, 0));
    PHASE(0, 0, 1, 0, ST_B(0, t2, 0));
    PHASE(0, 1, 1, 0, ST_B(0, t2, 1));
    PHASE(1, 0, 1, 0, ST_A(0, t2, 1));
    PHASE(1, 1, 1, 1, ST_A(1, t3, 0));
  }

  if (OUTMODE == 1) {
    const bool up = (bn >= 12);
#pragma unroll
    for (int m16 = 0; m16 < 16; ++m16) {
#pragma unroll
      for (int nr = 0; nr < 2; ++nr) {
        int grow = bm * 256 + m16 * 16 + ((lane >> 4) * 4);
        int gcol = bn * 256 + wn * 32 + nr * 16 + frow;
        if (!up) {
          u16* cp = C0 + (size_t)grow * (3 * DMODEL) + gcol;
#pragma unroll
          for (int r = 0; r < 4; ++r) cp[(size_t)r * (3 * DMODEL)] = f2bf(acc[m16][nr][r]);
        } else {
          u16* cp = C1 + (size_t)grow * FCAT + (gcol - 2048);
#pragma unroll
          for (int r = 0; r < 4; ++r) cp[(size_t)r * FCAT] = f2bf(gelu_f(acc[m16][nr][r]));
        }
      }
    }
  } else {
    u16* Cp = C0 + (size_t)blockIdx.y * M * N;
#pragma unroll
    for (int m16 = 0; m16 < 16; ++m16) {
#pragma unroll
      for (int nr = 0; nr < 2; ++nr) {
        int grow = bm * 256 + m16 * 16 + ((lane >> 4) * 4);
        int gcol = bn * 256 + wn * 32 + nr * 16 + frow;
        u16* cp = Cp + (size_t)grow * N + gcol;
#pragma unroll
        for (int r = 0; r < 4; ++r) cp[(size_t)r * N] = f2bf(acc[m16][nr][r]);
      }
    }
  }
}

// ---------------- combine 8 bf16 split-K partials + skip -> f32 out ----------------
__global__ __launch_bounds__(256) void combine8(const u16* __restrict__ part,
                                                const float* __restrict__ x,
                                                float* __restrict__ out) {
  size_t i = (size_t)(blockIdx.x * 256 + threadIdx.x) * 8;
  float4 x0 = *(const float4*)(x + i);
  float4 x1 = *(const float4*)(x + i + 4);
  float s[8] = {x0.x, x0.y, x0.z, x0.w, x1.x, x1.y, x1.z, x1.w};
#pragma unroll
  for (int p = 0; p < 8; ++p) {
    u16x8 v = *(const u16x8*)(part + (size_t)p * (L_SEQ * DMODEL) + i);
#pragma unroll
    for (int j = 0; j < 8; ++j) s[j] += bf2f(v[j]);
  }
  float4 o0 = {s[0], s[1], s[2], s[3]};
  float4 o1 = {s[4], s[5], s[6], s[7]};
  *(float4*)(out + i) = o0;
  *(float4*)(out + i + 4) = o1;
}

// ---------------- q/k norm + RoPE + v copy (proj stride 3072) ----------------
// q additionally scaled by LOG2E so attention softmax can use exp2 directly.
__global__ __launch_bounds__(256) void qkv_prep(const u16* __restrict__ proj,
                                                const float* __restrict__ theta,
                                                const float* __restrict__ attn_scale,
                                                u16* __restrict__ qb, u16* __restrict__ kb,
                                                u16* __restrict__ vb) {
  const int l = blockIdx.x * 4 + (threadIdx.x >> 6);
  const int hd = blockIdx.y;
  const int e = threadIdx.x & 63;
  const u16* pr = proj + (size_t)l * (3 * DMODEL) + hd * EHEAD + e;
  float q = bf2f(pr[0]);
  float k = bf2f(pr[DMODEL]);
  float v = bf2f(pr[2 * DMODEL]);
  float sq = q * q, sk = k * k;
#pragma unroll
  for (int m = 1; m < 64; m <<= 1) {
    sq += __shfl_xor(sq, m);
    sk += __shfl_xor(sk, m);
  }
  float s = sqrtf(attn_scale[hd]);
  q *= LOG2E * s * rsqrtf(sq + 1e-6f);
  k *= s * rsqrtf(sk + 1e-6f);
  float ang = theta[((size_t)hd * L_SEQ + l) * 32 + (e & 31)];
  float cs = __cosf(ang), sn = __sinf(ang);
  float qp = __shfl_xor(q, 32), kp = __shfl_xor(k, 32);
  float qr = (e < 32) ? (q * cs - qp * sn) : (q * cs + qp * sn);
  float kr = (e < 32) ? (k * cs - kp * sn) : (k * cs + kp * sn);
  size_t o = ((size_t)hd * L_SEQ + l) * EHEAD + e;
  qb[o] = f2bf(qr);
  kb[o] = f2bf(kr);
  vb[o] = f2bf(v);
}

// ---------------- causal flash attention, split-KV x4, 32x32 MFMA ----------------
// 2048 blocks x 128 threads (2 waves), 4 waves/SIMD occupancy.
// Block b: strip s = 31-(b>>6) (heavy-first), head = (b>>2)&15, chunk c = b&3.
// Chunk processes tiles [c*nt/4, (c+1)*nt/4) of nt = s+1; writes unnormalized
// partial O_c (bf16 64x64) + m_c, l_c (f32, log2-domain) for the merge pass.
__global__ __launch_bounds__(128, 4) void attn_kernel(const u16* __restrict__ qb,
                                                      const u16* __restrict__ kb,
                                                      const u16* __restrict__ vb,
                                                      u16* __restrict__ po,
                                                      float* __restrict__ pm,
                                                      float* __restrict__ pl) {
  const int bid = blockIdx.x;
  const int s = 31 - (bid >> 6);
  const int hd = (bid >> 2) & 15;
  const int c = bid & 3;
  const int tid = threadIdx.x;
  const int lane = tid & 63;
  const int w = tid >> 6;
  const int h = lane >> 5;
  const int ql = lane & 31;
  const int qg = s * 64 + w * 32 + ql;
  const int nt = s + 1;
  const int t0 = (c * nt) >> 2;
  const int t1 = ((c + 1) * nt) >> 2;

  __shared__ u16 sK[64 * 64];
  __shared__ u16 sVT[64 * 64];

  const u16* Kh = kb + (size_t)hd * L_SEQ * EHEAD;
  const u16* Vh = vb + (size_t)hd * L_SEQ * EHEAD;
  const u16* Qh = qb + (size_t)hd * L_SEQ * EHEAD;

  bf16x8 qf[4];
#pragma unroll
  for (int es = 0; es < 4; ++es)
    qf[es] = *(const bf16x8*)(Qh + (size_t)qg * EHEAD + es * 16 + h * 8);

  f32x16 oa[2] = {};
  float m = NEGINF, lsum = 0.0f;

  const int vk = (tid & 15) * 4;
  const int ve = (tid >> 4) * 8;

  for (int kt = t0; kt < t1; ++kt) {
    const int k0 = kt * 64;
    __syncthreads();
#pragma unroll
    for (int i = 0; i < 4; ++i) {
      int r = w * 32 + i * 8 + (lane >> 3);
      const u16* src = Kh + (size_t)(k0 + r) * EHEAD + (((lane & 7) ^ (r & 7)) << 3);
      gld16(sK + (w * 32 + i * 8) * 64 + lane * 8, src);
    }
    u16x8 vr[4];
#pragma unroll
    for (int j = 0; j < 4; ++j)
      vr[j] = *(const u16x8*)(Vh + (size_t)(k0 + vk + j) * EHEAD + ve);
#pragma unroll
    for (int e = 0; e < 8; ++e) {
      int row = ve + e;
      int boff = row * 128 + ((((vk >> 3) ^ (row & 7)) << 4) | ((vk & 4) << 1));
      ushort4 pv;
      pv.x = vr[0][e]; pv.y = vr[1][e]; pv.z = vr[2][e]; pv.w = vr[3][e];
      *(ushort4*)((char*)sVT + boff) = pv;
    }
    __syncthreads();

    f32x16 st[2];
#pragma unroll
    for (int t = 0; t < 2; ++t) {
      f32x16 a = {};
      __builtin_amdgcn_s_setprio(1);
#pragma unroll
      for (int es = 0; es < 4; ++es) {
        int row = t * 32 + ql;
        int boff = row * 128 + (((es * 2 + h) ^ (row & 7)) << 4);
        bf16x8 kf = *(const bf16x8*)((const char*)sK + boff);
        a = __builtin_amdgcn_mfma_f32_32x32x16_bf16(kf, qf[es], a, 0, 0, 0);
      }
      __builtin_amdgcn_s_setprio(0);
      st[t] = a;
    }

    float p[2][16];
    float mx = NEGINF;
    const bool edge = (kt == s);
#pragma unroll
    for (int t = 0; t < 2; ++t)
#pragma unroll
      for (int r = 0; r < 16; ++r) {
        float v = st[t][r];
        if (edge) {
          int kg = k0 + t * 32 + (r & 3) + ((r >> 2) << 3) + h * 4;
          v = (kg > qg) ? NEGINF : v;
        }
        p[t][r] = v;
        mx = fmaxf(mx, v);
      }
    mx = fmaxf(mx, __shfl_xor(mx, 32));
    // defer-max (T13): only rescale when the running max moved materially
    if (!__all(mx - m <= 8.0f)) {
      float mnew = fmaxf(m, mx);
      float alpha = EXP2F(m - mnew);
      lsum *= alpha;
#pragma unroll
      for (int et = 0; et < 2; ++et)
#pragma unroll
        for (int r = 0; r < 16; ++r) oa[et][r] *= alpha;
      m = mnew;
    }
    float ps = 0.0f;
#pragma unroll
    for (int t = 0; t < 2; ++t)
#pragma unroll
      for (int r = 0; r < 16; ++r) {
        float e_ = EXP2F(p[t][r] - m);
        p[t][r] = e_;
        ps += e_;
      }
    ps += __shfl_xor(ps, 32);
    lsum += ps;

    // pack P to bf16 pairs via cvt_pk (lo = p[2i], hi = p[2i+1])
    u32 pk_[2][8];
#pragma unroll
    for (int t = 0; t < 2; ++t)
#pragma unroll
      for (int i = 0; i < 8; ++i)
        asm("v_cvt_pk_bf16_f32 %0, %1, %2" : "=v"(pk_[t][i]) : "v"(p[t][2 * i]), "v"(p[t][2 * i + 1]));

#pragma unroll
    for (int ks = 0; ks < 4; ++ks) {
      const int tp = ks >> 1, base = (ks & 1) * 4;
      u32 s0 = h ? pk_[tp][base + 0] : pk_[tp][base + 2];
      u32 s1 = h ? pk_[tp][base + 1] : pk_[tp][base + 3];
      u32 r0 = (u32)__shfl_xor((int)s0, 32);
      u32 r1 = (u32)__shfl_xor((int)s1, 32);
      union { u32 u[4]; bf16x8 v; } pf;
      pf.u[0] = h ? r0 : pk_[tp][base + 0];
      pf.u[1] = h ? r1 : pk_[tp][base + 1];
      pf.u[2] = h ? pk_[tp][base + 2] : r0;
      pf.u[3] = h ? pk_[tp][base + 3] : r1;
      __builtin_amdgcn_s_setprio(1);
#pragma unroll
      for (int et = 0; et < 2; ++et) {
        int row = et * 32 + ql;
        int boff = row * 128 + (((ks * 2 + h) ^ (row & 7)) << 4);
        bf16x8 vf = *(const bf16x8*)((const char*)sVT + boff);
        oa[et] = __builtin_amdgcn_mfma_f32_32x32x16_bf16(vf, pf.v, oa[et], 0, 0, 0);
      }
      __builtin_amdgcn_s_setprio(0);
    }
  }

  // epilogue: write unnormalized partial O_c + (m, l)
  const size_t pidx = (size_t)(s * 16 + hd) * 4 + c;
  u16* orow = po + pidx * 4096 + (size_t)(w * 32 + ql) * 64;
#pragma unroll
  for (int et = 0; et < 2; ++et)
#pragma unroll
    for (int g = 0; g < 4; ++g) {
      ushort4 ov;
      ov.x = f2bf(oa[et][4 * g + 0]);
      ov.y = f2bf(oa[et][4 * g + 1]);
      ov.z = f2bf(oa[et][4 * g + 2]);
      ov.w = f2bf(oa[et][4 * g + 3]);
      *(ushort4*)(orow + et * 32 + g * 8 + h * 4) = ov;
    }
  if (h == 0) {
    pm[pidx * 64 + w * 32 + ql] = m;
    pl[pidx * 64 + w * 32 + ql] = lsum;
  }
}

// ---------------- merge split-KV partials -> hb ----------------
__global__ __launch_bounds__(256) void attn_merge(const u16* __restrict__ po,
                                                  const float* __restrict__ pm,
                                                  const float* __restrict__ pl,
                                                  u16* __restrict__ hb) {
  const int sh = blockIdx.x;        // s*16 + hd
  const int s = sh >> 4, hd = sh & 15;
  const int r = threadIdx.x >> 2;
  const int ec = (threadIdx.x & 3) << 4;
  float mc[4], wgt[4];
  float M = NEGINF;
#pragma unroll
  for (int c = 0; c < 4; ++c) {
    mc[c] = pm[(size_t)(sh * 4 + c) * 64 + r];
    M = fmaxf(M, mc[c]);
  }
  float L = 0.0f;
#pragma unroll
  for (int c = 0; c < 4; ++c) {
    wgt[c] = EXP2F(mc[c] - M);
    L += pl[(size_t)(sh * 4 + c) * 64 + r] * wgt[c];
  }
  float inv = 1.0f / L;
  float o[16] = {};
#pragma unroll
  for (int c = 0; c < 4; ++c) {
    const u16* pp = po + (size_t)(sh * 4 + c) * 4096 + r * 64 + ec;
    u16x8 v0 = *(const u16x8*)pp;
    u16x8 v1 = *(const u16x8*)(pp + 8);
#pragma unroll
    for (int j = 0; j < 8; ++j) {
      o[j] += wgt[c] * bf2f(v0[j]);
      o[8 + j] += wgt[c] * bf2f(v1[j]);
    }
  }
  u16* dst = hb + (size_t)(s * 64 + r) * FCAT + hd * EHEAD + ec;
  u16x8 out0, out1;
#pragma unroll
  for (int j = 0; j < 8; ++j) {
    out0[j] = f2bf(o[j] * inv);
    out1[j] = f2bf(o[8 + j] * inv);
  }
  *(u16x8*)dst = out0;
  *(u16x8*)(dst + 8) = out1;
}

extern "C" void kernel_launch(void* const* d_in, const int* in_sizes, int n_in,
                              void* d_out, int out_size, void* d_ws, size_t ws_size,
                              hipStream_t stream) {
  const float* x = (const float*)d_in[0];
  const float* theta = (const float*)d_in[1];
  const float* scale = (const float*)d_in[2];
  const float* w_in = (const float*)d_in[3];
  const float* w_out = (const float*)d_in[4];
  const float* attn_scale = (const float*)d_in[5];
  float* out = (float*)d_out;

  char* ws = (char*)d_ws;
  u16* w_out_b = (u16*)ws;   ws += (size_t)DMODEL * FCAT * 2;        // live: GEMM2 B
  u16* hb = (u16*)ws;        ws += (size_t)L_SEQ * FCAT * 2;         // live: GEMM2 A
  u16* xn = (u16*)ws;        ws += (size_t)L_SEQ * DMODEL * 2;       // dead after GEMM1
  u16* w_in_b = (u16*)ws;    ws += (size_t)FPROJ * DMODEL * 2;       // dead after GEMM1
  u16* proj = (u16*)ws;      ws += (size_t)L_SEQ * 3 * DMODEL * 2;   // dead after qkv_prep
  u16* qb = (u16*)ws;        ws += (size_t)NHEAD * L_SEQ * EHEAD * 2;
  u16* kb = (u16*)ws;        ws += (size_t)NHEAD * L_SEQ * EHEAD * 2;
  u16* vb = (u16*)ws;        ws += (size_t)NHEAD * L_SEQ * EHEAD * 2;
  // attention partials overlay dead xn+w_in_b (18.9MB): po 16.8MB + pm/pl 1MB
  u16* po = xn;
  float* pm = (float*)(po + (size_t)512 * 4 * 4096);
  float* pl = pm + 512 * 4 * 64;
  // GEMM2 split-K partials (33.5MB) also overlay xn.. — written after attn_merge
  u16* part = xn;

  cvt_kernel<<<7168, 256, 0, stream>>>(w_in, w_in_b, FPROJ * DMODEL / 4);
  cvt_kernel<<<5120, 256, 0, stream>>>(w_out, w_out_b, DMODEL * FCAT / 4);
  rmsnorm_kernel<<<L_SEQ, 256, 0, stream>>>(x, scale, xn);
  gemm256<1><<<(L_SEQ / 256) * (FPROJ / 256), 512, 0, stream>>>(xn, w_in_b, proj, hb,
                                                                L_SEQ, FPROJ, DMODEL);
  qkv_prep<<<dim3(L_SEQ / 4, NHEAD), 256, 0, stream>>>(proj, theta, attn_scale, qb, kb, vb);
  attn_kernel<<<2048, 128, 0, stream>>>(qb, kb, vb, po, pm, pl);
  attn_merge<<<512, 256, 0, stream>>>(po, pm, pl, hb);
  gemm256<2><<<dim3((L_SEQ / 256) * (DMODEL / 256), 8), 512, 0, stream>>>(hb, w_out_b, part,
                                                                          nullptr, L_SEQ, DMODEL, FCAT);
  combine8<<<L_SEQ * DMODEL / 8 / 256, 256, 0, stream>>>(part, x, out);
}

// Round 8
// 139.349 us; speedup vs baseline: 2.2493x; 1.0374x over previous
//
#include <hip/hip_runtime.h>

typedef unsigned short u16;
typedef unsigned int u32;
typedef __attribute__((ext_vector_type(8))) short bf16x8;
typedef __attribute__((ext_vector_type(8))) unsigned short u16x8;
typedef __attribute__((ext_vector_type(4))) float f32x4;
typedef __attribute__((ext_vector_type(16))) float f32x16;

#define L_SEQ 2048
#define DMODEL 1024
#define NHEAD 16
#define EHEAD 64
#define FPROJ 7168
#define FCAT 5120
#define NEGINF -1e30f
#define LOG2E 1.44269504088896f
#define EXP2F(x) __builtin_amdgcn_exp2f(x)

__device__ __forceinline__ u16 f2bf(float f) {
  union { float f; u32 u; } v; v.f = f;
  u32 r = v.u + 0x7FFFu + ((v.u >> 16) & 1u);
  return (u16)(r >> 16);
}
__device__ __forceinline__ float bf2f(u16 h) {
  union { u32 u; float f; } v; v.u = ((u32)h) << 16;
  return v.f;
}
__device__ __forceinline__ float gelu_f(float x) {
  float y = 0.7978845608028654f * (x + 0.044715f * x * x * x);
  float t = __expf(-2.0f * fabsf(y));
  float th = (1.0f - t) / (1.0f + t);
  th = (y < 0.0f) ? -th : th;
  return 0.5f * x * (1.0f + th);
}
__device__ __forceinline__ void gld16(void* lds, const void* g) {
  __builtin_amdgcn_global_load_lds((const __attribute__((address_space(1))) u32*)g,
                                   (__attribute__((address_space(3))) u32*)lds, 16, 0, 0);
}

// ---------------- f32 -> bf16 convert (both weights, one dispatch) ----------------
__global__ __launch_bounds__(256) void cvt2_kernel(const float* __restrict__ a,
                                                   u16* __restrict__ oa, int na4,
                                                   const float* __restrict__ b,
                                                   u16* __restrict__ ob, int nb4) {
  int i = blockIdx.x * 256 + threadIdx.x;
  const float* src;
  u16* dst;
  int j;
  if (i < na4) {
    src = a; dst = oa; j = i;
  } else {
    j = i - na4;
    if (j >= nb4) return;
    src = b; dst = ob;
  }
  float4 v = ((const float4*)src)[j];
  ((u32*)dst)[2 * j] = (u32)f2bf(v.x) | ((u32)f2bf(v.y) << 16);
  ((u32*)dst)[2 * j + 1] = (u32)f2bf(v.z) | ((u32)f2bf(v.w) << 16);
}

// ---------------- RMSNorm * (1+scale) -> bf16 ----------------
__global__ __launch_bounds__(256) void rmsnorm_kernel(const float* __restrict__ x,
                                                      const float* __restrict__ scale,
                                                      u16* __restrict__ xn) {
  int row = blockIdx.x;
  const float4 v = ((const float4*)(x + (size_t)row * DMODEL))[threadIdx.x];
  float ss = v.x * v.x + v.y * v.y + v.z * v.z + v.w * v.w;
#pragma unroll
  for (int m = 1; m < 64; m <<= 1) ss += __shfl_xor(ss, m);
  __shared__ float ws[4];
  if ((threadIdx.x & 63) == 0) ws[threadIdx.x >> 6] = ss;
  __syncthreads();
  float tot = ws[0] + ws[1] + ws[2] + ws[3];
  float r = rsqrtf(tot * (1.0f / DMODEL) + 1e-6f);
  float4 sc = ((const float4*)scale)[threadIdx.x];
  u32 w0 = (u32)f2bf(v.x * r * (1.0f + sc.x)) | ((u32)f2bf(v.y * r * (1.0f + sc.y)) << 16);
  u32 w1 = (u32)f2bf(v.z * r * (1.0f + sc.z)) | ((u32)f2bf(v.w * r * (1.0f + sc.w)) << 16);
  u32* dst = (u32*)(xn + (size_t)row * DMODEL);
  dst[2 * threadIdx.x] = w0;
  dst[2 * threadIdx.x + 1] = w1;
}

// ---------------- 256x256 8-phase GEMM (round-4 notes) ----------------
// Column-major XCD map: each XCD's contiguous v-range covers few bn-panels
// (B near-single-fetch) instead of re-reading B across all 8 XCDs.
__device__ __forceinline__ void stage_half(u16* lds, const u16* g, int K, int tid) {
#pragma unroll
  for (int i = 0; i < 2; ++i) {
    int idx = tid + i * 512;
    int r = idx >> 3;
    int gcb = ((idx & 7) << 4) ^ ((r & 7) << 4);
    gld16((char*)lds + idx * 16, (const char*)g + (size_t)r * K * 2 + gcb);
  }
}

#define GFENCE asm volatile("" ::: "memory")
#define VMW2 asm volatile("s_waitcnt vmcnt(2)" ::: "memory")
#define ST_A(BUF, T, HALF) stage_half(sA + (BUF) * 16384 + (HALF) * 8192, \
    Ab + (size_t)((HALF) * 128) * K + (T) * 64, K, tid)
#define ST_B(BUF, T, HALF) stage_half(sB + (BUF) * 16384 + (HALF) * 8192, \
    Bb + (size_t)((HALF) * 128) * K + (T) * 64, K, tid)

#define PHASE(HM, KH, BUFB, DOVM, STCODE) do { \
    const char* ab_ = (const char*)sA + (BUFB) * 32768 + (HM) * 16384 + frow * 128 + ((KH) ? co1 : co0); \
    const char* bb_ = (const char*)sB + (BUFB) * 32768 + (wn * 32 + frow) * 128 + ((KH) ? co1 : co0); \
    bf16x8 af_[8], bv_[2]; \
    _Pragma("unroll") \
    for (int mr = 0; mr < 8; ++mr) af_[mr] = *(const bf16x8*)(ab_ + mr * 2048); \
    bv_[0] = *(const bf16x8*)(bb_); \
    bv_[1] = *(const bf16x8*)(bb_ + 2048); \
    GFENCE; \
    STCODE; \
    if (DOVM) VMW2; \
    __builtin_amdgcn_s_barrier(); \
    __builtin_amdgcn_s_setprio(1); \
    _Pragma("unroll") \
    for (int mr = 0; mr < 8; ++mr) { \
      acc[(HM) * 8 + mr][0] = __builtin_amdgcn_mfma_f32_16x16x32_bf16(af_[mr], bv_[0], acc[(HM) * 8 + mr][0], 0, 0, 0); \
      acc[(HM) * 8 + mr][1] = __builtin_amdgcn_mfma_f32_16x16x32_bf16(af_[mr], bv_[1], acc[(HM) * 8 + mr][1], 0, 0, 0); \
    } \
    __builtin_amdgcn_s_setprio(0); \
    __builtin_amdgcn_s_barrier(); \
  } while (0)

template <int OUTMODE>
__global__ __launch_bounds__(512, 2) void gemm256(const u16* __restrict__ A,
                                                  const u16* __restrict__ B,
                                                  u16* __restrict__ C0,
                                                  u16* __restrict__ C1,
                                                  int M, int N, int K) {
  __shared__ __align__(16) u16 sA[2 * 16384];
  __shared__ __align__(16) u16 sB[2 * 16384];
  const int tid = threadIdx.x;
  const int lane = tid & 63;
  const int wn = tid >> 6;
  const int frow = lane & 15;
  const int kbyte = ((lane >> 4) & 3) << 4;
  const int sw = (frow & 7) << 4;
  const int co0 = kbyte ^ sw;
  const int co1 = (64 | kbyte) ^ sw;

  const int nbx = N >> 8;
  const int nbm = (int)gridDim.x / nbx;   // M/256
  const int v = (blockIdx.x & 7) * ((int)gridDim.x >> 3) + ((int)blockIdx.x >> 3);
  const int bm = v % nbm, bn = v / nbm;   // column-major: XCD range spans few bn
  const int kper = K / (int)gridDim.y;
  const int kbeg = blockIdx.y * kper;
  const u16* Ab = A + (size_t)(bm * 256) * K + kbeg;
  const u16* Bb = B + (size_t)(bn * 256) * K + kbeg;

  f32x4 acc[16][2] = {};

  const int NT = kper >> 6;
  ST_A(0, 0, 0); ST_B(0, 0, 0); ST_B(0, 0, 1); ST_A(0, 0, 1); ST_A(1, 1, 0);
  VMW2;
  __builtin_amdgcn_s_barrier();

  for (int kt = 0; kt < NT; kt += 2) {
    const int t1 = kt + 1;
    const int t2 = (kt + 2 >= NT) ? kt + 2 - NT : kt + 2;
    const int t3 = (kt + 3 >= NT) ? kt + 3 - NT : kt + 3;
    PHASE(0, 0, 0, 0, ST_B(1, t1, 0));
    PHASE(0, 1, 0, 0, ST_B(1, t1, 1));
    PHASE(1, 0, 0, 0, ST_A(1, t1, 1));
    PHASE(1, 1, 0, 1, ST_A(0, t2, 0));
    PHASE(0, 0, 1, 0, ST_B(0, t2, 0));
    PHASE(0, 1, 1, 0, ST_B(0, t2, 1));
    PHASE(1, 0, 1, 0, ST_A(0, t2, 1));
    PHASE(1, 1, 1, 1, ST_A(1, t3, 0));
  }

  if (OUTMODE == 1) {
    const bool up = (bn >= 12);
#pragma unroll
    for (int m16 = 0; m16 < 16; ++m16) {
#pragma unroll
      for (int nr = 0; nr < 2; ++nr) {
        int grow = bm * 256 + m16 * 16 + ((lane >> 4) * 4);
        int gcol = bn * 256 + wn * 32 + nr * 16 + frow;
        if (!up) {
          u16* cp = C0 + (size_t)grow * (3 * DMODEL) + gcol;
#pragma unroll
          for (int r = 0; r < 4; ++r) cp[(size_t)r * (3 * DMODEL)] = f2bf(acc[m16][nr][r]);
        } else {
          u16* cp = C1 + (size_t)grow * FCAT + (gcol - 2048);
#pragma unroll
          for (int r = 0; r < 4; ++r) cp[(size_t)r * FCAT] = f2bf(gelu_f(acc[m16][nr][r]));
        }
      }
    }
  } else {
    u16* Cp = C0 + (size_t)blockIdx.y * M * N;
#pragma unroll
    for (int m16 = 0; m16 < 16; ++m16) {
#pragma unroll
      for (int nr = 0; nr < 2; ++nr) {
        int grow = bm * 256 + m16 * 16 + ((lane >> 4) * 4);
        int gcol = bn * 256 + wn * 32 + nr * 16 + frow;
        u16* cp = Cp + (size_t)grow * N + gcol;
#pragma unroll
        for (int r = 0; r < 4; ++r) cp[(size_t)r * N] = f2bf(acc[m16][nr][r]);
      }
    }
  }
}

// ---------------- combine 8 bf16 split-K partials + skip -> f32 out ----------------
__global__ __launch_bounds__(256) void combine8(const u16* __restrict__ part,
                                                const float* __restrict__ x,
                                                float* __restrict__ out) {
  size_t i = (size_t)(blockIdx.x * 256 + threadIdx.x) * 8;
  float4 x0 = *(const float4*)(x + i);
  float4 x1 = *(const float4*)(x + i + 4);
  float s[8] = {x0.x, x0.y, x0.z, x0.w, x1.x, x1.y, x1.z, x1.w};
#pragma unroll
  for (int p = 0; p < 8; ++p) {
    u16x8 v = *(const u16x8*)(part + (size_t)p * (L_SEQ * DMODEL) + i);
#pragma unroll
    for (int j = 0; j < 8; ++j) s[j] += bf2f(v[j]);
  }
  float4 o0 = {s[0], s[1], s[2], s[3]};
  float4 o1 = {s[4], s[5], s[6], s[7]};
  *(float4*)(out + i) = o0;
  *(float4*)(out + i + 4) = o1;
}

// ---------------- q/k norm + RoPE + v copy (proj stride 3072) ----------------
__global__ __launch_bounds__(256) void qkv_prep(const u16* __restrict__ proj,
                                                const float* __restrict__ theta,
                                                const float* __restrict__ attn_scale,
                                                u16* __restrict__ qb, u16* __restrict__ kb,
                                                u16* __restrict__ vb) {
  const int l = blockIdx.x * 4 + (threadIdx.x >> 6);
  const int hd = blockIdx.y;
  const int e = threadIdx.x & 63;
  const u16* pr = proj + (size_t)l * (3 * DMODEL) + hd * EHEAD + e;
  float q = bf2f(pr[0]);
  float k = bf2f(pr[DMODEL]);
  float v = bf2f(pr[2 * DMODEL]);
  float sq = q * q, sk = k * k;
#pragma unroll
  for (int m = 1; m < 64; m <<= 1) {
    sq += __shfl_xor(sq, m);
    sk += __shfl_xor(sk, m);
  }
  float s = sqrtf(attn_scale[hd]);
  q *= LOG2E * s * rsqrtf(sq + 1e-6f);
  k *= s * rsqrtf(sk + 1e-6f);
  float ang = theta[((size_t)hd * L_SEQ + l) * 32 + (e & 31)];
  float cs = __cosf(ang), sn = __sinf(ang);
  float qp = __shfl_xor(q, 32), kp = __shfl_xor(k, 32);
  float qr = (e < 32) ? (q * cs - qp * sn) : (q * cs + qp * sn);
  float kr = (e < 32) ? (k * cs - kp * sn) : (k * cs + kp * sn);
  size_t o = ((size_t)hd * L_SEQ + l) * EHEAD + e;
  qb[o] = f2bf(qr);
  kb[o] = f2bf(kr);
  vb[o] = f2bf(v);
}

// ---------------- causal flash attention, split-KV x4, 32x32 MFMA ----------------
__global__ __launch_bounds__(128, 4) void attn_kernel(const u16* __restrict__ qb,
                                                      const u16* __restrict__ kb,
                                                      const u16* __restrict__ vb,
                                                      u16* __restrict__ po,
                                                      float* __restrict__ pm,
                                                      float* __restrict__ pl) {
  const int bid = blockIdx.x;
  const int s = 31 - (bid >> 6);
  const int hd = (bid >> 2) & 15;
  const int c = bid & 3;
  const int tid = threadIdx.x;
  const int lane = tid & 63;
  const int w = tid >> 6;
  const int h = lane >> 5;
  const int ql = lane & 31;
  const int qg = s * 64 + w * 32 + ql;
  const int nt = s + 1;
  const int t0 = (c * nt) >> 2;
  const int t1 = ((c + 1) * nt) >> 2;

  __shared__ u16 sK[64 * 64];
  __shared__ u16 sVT[64 * 64];

  const u16* Kh = kb + (size_t)hd * L_SEQ * EHEAD;
  const u16* Vh = vb + (size_t)hd * L_SEQ * EHEAD;
  const u16* Qh = qb + (size_t)hd * L_SEQ * EHEAD;

  bf16x8 qf[4];
#pragma unroll
  for (int es = 0; es < 4; ++es)
    qf[es] = *(const bf16x8*)(Qh + (size_t)qg * EHEAD + es * 16 + h * 8);

  f32x16 oa[2] = {};
  float m = NEGINF, lsum = 0.0f;

  const int vk = (tid & 15) * 4;
  const int ve = (tid >> 4) * 8;

  for (int kt = t0; kt < t1; ++kt) {
    const int k0 = kt * 64;
    __syncthreads();
#pragma unroll
    for (int i = 0; i < 4; ++i) {
      int r = w * 32 + i * 8 + (lane >> 3);
      const u16* src = Kh + (size_t)(k0 + r) * EHEAD + (((lane & 7) ^ (r & 7)) << 3);
      gld16(sK + (w * 32 + i * 8) * 64 + lane * 8, src);
    }
    u16x8 vr[4];
#pragma unroll
    for (int j = 0; j < 4; ++j)
      vr[j] = *(const u16x8*)(Vh + (size_t)(k0 + vk + j) * EHEAD + ve);
#pragma unroll
    for (int e = 0; e < 8; ++e) {
      int row = ve + e;
      int boff = row * 128 + ((((vk >> 3) ^ (row & 7)) << 4) | ((vk & 4) << 1));
      ushort4 pv;
      pv.x = vr[0][e]; pv.y = vr[1][e]; pv.z = vr[2][e]; pv.w = vr[3][e];
      *(ushort4*)((char*)sVT + boff) = pv;
    }
    __syncthreads();

    f32x16 st[2];
#pragma unroll
    for (int t = 0; t < 2; ++t) {
      f32x16 a = {};
      __builtin_amdgcn_s_setprio(1);
#pragma unroll
      for (int es = 0; es < 4; ++es) {
        int row = t * 32 + ql;
        int boff = row * 128 + (((es * 2 + h) ^ (row & 7)) << 4);
        bf16x8 kf = *(const bf16x8*)((const char*)sK + boff);
        a = __builtin_amdgcn_mfma_f32_32x32x16_bf16(kf, qf[es], a, 0, 0, 0);
      }
      __builtin_amdgcn_s_setprio(0);
      st[t] = a;
    }

    float p[2][16];
    float mx = NEGINF;
    const bool edge = (kt == s);
#pragma unroll
    for (int t = 0; t < 2; ++t)
#pragma unroll
      for (int r = 0; r < 16; ++r) {
        float v = st[t][r];
        if (edge) {
          int kg = k0 + t * 32 + (r & 3) + ((r >> 2) << 3) + h * 4;
          v = (kg > qg) ? NEGINF : v;
        }
        p[t][r] = v;
        mx = fmaxf(mx, v);
      }
    mx = fmaxf(mx, __shfl_xor(mx, 32));
    if (!__all(mx - m <= 8.0f)) {
      float mnew = fmaxf(m, mx);
      float alpha = EXP2F(m - mnew);
      lsum *= alpha;
#pragma unroll
      for (int et = 0; et < 2; ++et)
#pragma unroll
        for (int r = 0; r < 16; ++r) oa[et][r] *= alpha;
      m = mnew;
    }
    float ps = 0.0f;
#pragma unroll
    for (int t = 0; t < 2; ++t)
#pragma unroll
      for (int r = 0; r < 16; ++r) {
        float e_ = EXP2F(p[t][r] - m);
        p[t][r] = e_;
        ps += e_;
      }
    ps += __shfl_xor(ps, 32);
    lsum += ps;

    u32 pk_[2][8];
#pragma unroll
    for (int t = 0; t < 2; ++t)
#pragma unroll
      for (int i = 0; i < 8; ++i)
        asm("v_cvt_pk_bf16_f32 %0, %1, %2" : "=v"(pk_[t][i]) : "v"(p[t][2 * i]), "v"(p[t][2 * i + 1]));

#pragma unroll
    for (int ks = 0; ks < 4; ++ks) {
      const int tp = ks >> 1, base = (ks & 1) * 4;
      u32 s0 = h ? pk_[tp][base + 0] : pk_[tp][base + 2];
      u32 s1 = h ? pk_[tp][base + 1] : pk_[tp][base + 3];
      u32 r0 = (u32)__shfl_xor((int)s0, 32);
      u32 r1 = (u32)__shfl_xor((int)s1, 32);
      union { u32 u[4]; bf16x8 v; } pf;
      pf.u[0] = h ? r0 : pk_[tp][base + 0];
      pf.u[1] = h ? r1 : pk_[tp][base + 1];
      pf.u[2] = h ? pk_[tp][base + 2] : r0;
      pf.u[3] = h ? pk_[tp][base + 3] : r1;
      __builtin_amdgcn_s_setprio(1);
#pragma unroll
      for (int et = 0; et < 2; ++et) {
        int row = et * 32 + ql;
        int boff = row * 128 + (((ks * 2 + h) ^ (row & 7)) << 4);
        bf16x8 vf = *(const bf16x8*)((const char*)sVT + boff);
        oa[et] = __builtin_amdgcn_mfma_f32_32x32x16_bf16(vf, pf.v, oa[et], 0, 0, 0);
      }
      __builtin_amdgcn_s_setprio(0);
    }
  }

  const size_t pidx = (size_t)(s * 16 + hd) * 4 + c;
  u16* orow = po + pidx * 4096 + (size_t)(w * 32 + ql) * 64;
#pragma unroll
  for (int et = 0; et < 2; ++et)
#pragma unroll
    for (int g = 0; g < 4; ++g) {
      ushort4 ov;
      ov.x = f2bf(oa[et][4 * g + 0]);
      ov.y = f2bf(oa[et][4 * g + 1]);
      ov.z = f2bf(oa[et][4 * g + 2]);
      ov.w = f2bf(oa[et][4 * g + 3]);
      *(ushort4*)(orow + et * 32 + g * 8 + h * 4) = ov;
    }
  if (h == 0) {
    pm[pidx * 64 + w * 32 + ql] = m;
    pl[pidx * 64 + w * 32 + ql] = lsum;
  }
}

// ---------------- merge split-KV partials -> hb ----------------
__global__ __launch_bounds__(256) void attn_merge(const u16* __restrict__ po,
                                                  const float* __restrict__ pm,
                                                  const float* __restrict__ pl,
                                                  u16* __restrict__ hb) {
  const int sh = blockIdx.x;
  const int s = sh >> 4, hd = sh & 15;
  const int r = threadIdx.x >> 2;
  const int ec = (threadIdx.x & 3) << 4;
  float mc[4], wgt[4];
  float M = NEGINF;
#pragma unroll
  for (int c = 0; c < 4; ++c) {
    mc[c] = pm[(size_t)(sh * 4 + c) * 64 + r];
    M = fmaxf(M, mc[c]);
  }
  float L = 0.0f;
#pragma unroll
  for (int c = 0; c < 4; ++c) {
    wgt[c] = EXP2F(mc[c] - M);
    L += pl[(size_t)(sh * 4 + c) * 64 + r] * wgt[c];
  }
  float inv = 1.0f / L;
  float o[16] = {};
#pragma unroll
  for (int c = 0; c < 4; ++c) {
    const u16* pp = po + (size_t)(sh * 4 + c) * 4096 + r * 64 + ec;
    u16x8 v0 = *(const u16x8*)pp;
    u16x8 v1 = *(const u16x8*)(pp + 8);
#pragma unroll
    for (int j = 0; j < 8; ++j) {
      o[j] += wgt[c] * bf2f(v0[j]);
      o[8 + j] += wgt[c] * bf2f(v1[j]);
    }
  }
  u16* dst = hb + (size_t)(s * 64 + r) * FCAT + hd * EHEAD + ec;
  u16x8 out0, out1;
#pragma unroll
  for (int j = 0; j < 8; ++j) {
    out0[j] = f2bf(o[j] * inv);
    out1[j] = f2bf(o[8 + j] * inv);
  }
  *(u16x8*)dst = out0;
  *(u16x8*)(dst + 8) = out1;
}

extern "C" void kernel_launch(void* const* d_in, const int* in_sizes, int n_in,
                              void* d_out, int out_size, void* d_ws, size_t ws_size,
                              hipStream_t stream) {
  const float* x = (const float*)d_in[0];
  const float* theta = (const float*)d_in[1];
  const float* scale = (const float*)d_in[2];
  const float* w_in = (const float*)d_in[3];
  const float* w_out = (const float*)d_in[4];
  const float* attn_scale = (const float*)d_in[5];
  float* out = (float*)d_out;

  char* ws = (char*)d_ws;
  u16* w_out_b = (u16*)ws;   ws += (size_t)DMODEL * FCAT * 2;        // live: GEMM2 B
  u16* hb = (u16*)ws;        ws += (size_t)L_SEQ * FCAT * 2;         // live: GEMM2 A
  u16* xn = (u16*)ws;        ws += (size_t)L_SEQ * DMODEL * 2;       // dead after GEMM1
  u16* w_in_b = (u16*)ws;    ws += (size_t)FPROJ * DMODEL * 2;       // dead after GEMM1
  u16* proj = (u16*)ws;      ws += (size_t)L_SEQ * 3 * DMODEL * 2;   // dead after qkv_prep
  u16* qb = (u16*)ws;        ws += (size_t)NHEAD * L_SEQ * EHEAD * 2;
  u16* kb = (u16*)ws;        ws += (size_t)NHEAD * L_SEQ * EHEAD * 2;
  u16* vb = (u16*)ws;        ws += (size_t)NHEAD * L_SEQ * EHEAD * 2;
  u16* po = xn;
  float* pm = (float*)(po + (size_t)512 * 4 * 4096);
  float* pl = pm + 512 * 4 * 64;
  u16* part = xn;

  const int na4 = FPROJ * DMODEL / 4, nb4 = DMODEL * FCAT / 4;
  cvt2_kernel<<<(na4 + nb4 + 255) / 256, 256, 0, stream>>>(w_in, w_in_b, na4,
                                                           w_out, w_out_b, nb4);
  rmsnorm_kernel<<<L_SEQ, 256, 0, stream>>>(x, scale, xn);
  gemm256<1><<<(L_SEQ / 256) * (FPROJ / 256), 512, 0, stream>>>(xn, w_in_b, proj, hb,
                                                                L_SEQ, FPROJ, DMODEL);
  qkv_prep<<<dim3(L_SEQ / 4, NHEAD), 256, 0, stream>>>(proj, theta, attn_scale, qb, kb, vb);
  attn_kernel<<<2048, 128, 0, stream>>>(qb, kb, vb, po, pm, pl);
  attn_merge<<<512, 256, 0, stream>>>(po, pm, pl, hb);
  gemm256<2><<<dim3((L_SEQ / 256) * (DMODEL / 256), 8), 512, 0, stream>>>(hb, w_out_b, part,
                                                                          nullptr, L_SEQ, DMODEL, FCAT);
  combine8<<<L_SEQ * DMODEL / 8 / 256, 256, 0, stream>>>(part, x, out);
}